// Round 5
// baseline (344.466 us; speedup 1.0000x reference)
//
#include <hip/hip_runtime.h>
#include <math.h>
#include <stdint.h>

#define NN 200000   // nodes
#define NQ 50000    // NN/4 column quads
#define DD 256      // feature dim
#define BB 256      // batch rows of adj
#define SS 512      // output samples
#define FW_BLOCKS 12500  // NN/16 rows-per-block for the fw2 stream

// PRNG: threefry_partitionable: elem i -> tf(0, i), bits = out0 ^ out1
// (verified bit-exact PASS, absmax 0.0, rounds 2-4)

typedef unsigned int u32;
typedef unsigned long long u64;
typedef float f4 __attribute__((ext_vector_type(4)));

__device__ __forceinline__ f4 ldnt4(const float* p) {
  return __builtin_nontemporal_load((const f4*)p);
}

// ---------------- threefry2x32, key = (0,1)  (jax.random.key(1)) ----------------
__device__ __forceinline__ uint2 tf2x32(u32 x0, u32 x1) {
  const u32 ks0 = 0u, ks1 = 1u, ks2 = 0x1BD11BDBu;
  x0 += ks0; x1 += ks1;
#define TFR(r) { x0 += x1; x1 = (x1 << (r)) | (x1 >> (32 - (r))); x1 ^= x0; }
  TFR(13) TFR(15) TFR(26) TFR(6)
  x0 += ks1; x1 += ks2 + 1u;
  TFR(17) TFR(29) TFR(16) TFR(24)
  x0 += ks2; x1 += ks0 + 2u;
  TFR(13) TFR(15) TFR(26) TFR(6)
  x0 += ks0; x1 += ks1 + 3u;
  TFR(17) TFR(29) TFR(16) TFR(24)
  x0 += ks1; x1 += ks2 + 4u;
  TFR(13) TFR(15) TFR(26) TFR(6)
  x0 += ks2; x1 += ks0 + 5u;
#undef TFR
  return make_uint2(x0, x1);
}

__device__ __forceinline__ float gumbel_from_bits(u32 bits) {
  const float TINY = 1.17549435e-38f;
  float f = __uint_as_float((bits >> 9) | 0x3f800000u) - 1.0f; // [0,1)
  float x = f + TINY;
  x = fmaxf(TINY, x);
  return -logf(-logf(x));
}

// pack (gumbel g, index n) so u64-max == (argmax g, first-index tie-break)
__device__ __forceinline__ u64 pack_key(float g, int n) {
  u32 u = __float_as_uint(g);
  u32 m = (u & 0x80000000u) ? ~u : (u | 0x80000000u);
  return ((u64)m << 32) | (u32)(~(u32)n);
}

// ---------------- kernels ----------------
// fused front: fw2 = feat@w2 (streaming, nontemporal), hw1 = feat[v]@w1,
// plus zeroing of s1/umask/means/scal/slots by the first 512 blocks
__global__ __launch_bounds__(256) void k_front(const float* __restrict__ feat,
                                               const float* __restrict__ w1,
                                               const float* __restrict__ w2,
                                               const int* __restrict__ v,
                                               float* __restrict__ fw2,
                                               float* __restrict__ hw1,
                                               float* __restrict__ s1,
                                               u32* __restrict__ umask,
                                               float* __restrict__ means,
                                               float* __restrict__ scal,
                                               u64* __restrict__ slots) {
  int blk = blockIdx.x;
  int wv = threadIdx.x >> 6;
  int lane = threadIdx.x & 63;
  if (blk < FW_BLOCKS) {
    int r0 = (blk * 4 + wv) * 4;
    f4 w4 = ((const f4*)w2)[lane];
    f4 f[4];
#pragma unroll
    for (int k = 0; k < 4; ++k)
      f[k] = ldnt4(feat + (size_t)(r0 + k) * DD + lane * 4);
    float d[4];
#pragma unroll
    for (int k = 0; k < 4; ++k)
      d[k] = f[k].x * w4.x + f[k].y * w4.y + f[k].z * w4.z + f[k].w * w4.w;
#pragma unroll
    for (int off = 32; off; off >>= 1) {
#pragma unroll
      for (int k = 0; k < 4; ++k) d[k] += __shfl_down(d[k], off);
    }
    if (lane == 0) {
#pragma unroll
      for (int k = 0; k < 4; ++k) fw2[r0 + k] = d[k];
    }
    if (blk < 512) {
      int i = blk * 256 + threadIdx.x;
      for (int j = i; j < NN; j += 512 * 256) { s1[j] = 0.0f; umask[j] = 0u; }
      if (i < 256) means[i] = 0.0f;
      if (i < 16) scal[i] = 0.0f;
      if (i < SS) slots[i] = 0ull;
    }
  } else {
    int r0 = ((blk - FW_BLOCKS) * 4 + wv) * 4;  // 0..255
    f4 w4 = ((const f4*)w1)[lane];
    f4 f[4];
#pragma unroll
    for (int k = 0; k < 4; ++k)
      f[k] = ((const f4*)(feat + (size_t)v[r0 + k] * DD))[lane];
    float d[4];
#pragma unroll
    for (int k = 0; k < 4; ++k)
      d[k] = f[k].x * w4.x + f[k].y * w4.y + f[k].z * w4.z + f[k].w * w4.w;
#pragma unroll
    for (int off = 32; off; off >>= 1) {
#pragma unroll
      for (int k = 0; k < 4; ++k) d[k] += __shfl_down(d[k], off);
    }
    if (lane == 0) {
#pragma unroll
      for (int k = 0; k < 4; ++k) hw1[r0 + k] = d[k];
    }
  }
}

// b-chunked column pass over adj: 8 chunks x 32 b, float4 columns, 8 loads in flight.
// col-mask via first-setter atomicExch (counts num_neis); s1 via sparse atomicAdd.
__global__ __launch_bounds__(256) void k_adj_partial(const float* __restrict__ adj,
                                                     const float* __restrict__ fw2,
                                                     const float* __restrict__ hw1,
                                                     float* __restrict__ s1,
                                                     u32* __restrict__ umask,
                                                     int* __restrict__ counters) {
  __shared__ float hs[BB];
  hs[threadIdx.x] = hw1[threadIdx.x] + 1.0f;
  __syncthreads();
  int cb = blockIdx.x % 196;
  int ch = blockIdx.x / 196;
  int q = cb * 256 + threadIdx.x;
  int newcnt = 0;
  if (q < NQ) {
    const float4* adj4 = (const float4*)adj;
    float4 fv = ((const float4*)fw2)[q];
    float csx = 0.f, csy = 0.f, csz = 0.f, csw = 0.f;
    float ssx = 0.f, ssy = 0.f, ssz = 0.f, ssw = 0.f;
    int b0 = ch * 32;
    for (int bb = 0; bb < 32; bb += 8) {
      float4 a[8];
#pragma unroll
      for (int k = 0; k < 8; ++k) a[k] = adj4[(size_t)(b0 + bb + k) * NQ + q];
#pragma unroll
      for (int k = 0; k < 8; ++k) {
        float h = hs[b0 + bb + k];
        csx += a[k].x; csy += a[k].y; csz += a[k].z; csw += a[k].w;
        ssx += a[k].x * fmaxf(h + fv.x, 0.f);
        ssy += a[k].y * fmaxf(h + fv.y, 0.f);
        ssz += a[k].z * fmaxf(h + fv.z, 0.f);
        ssw += a[k].w * fmaxf(h + fv.w, 0.f);
      }
    }
    int n0 = q * 4;
    if (csx > 0.f) newcnt += (atomicExch(&umask[n0 + 0], 1u) == 0u);
    if (csy > 0.f) newcnt += (atomicExch(&umask[n0 + 1], 1u) == 0u);
    if (csz > 0.f) newcnt += (atomicExch(&umask[n0 + 2], 1u) == 0u);
    if (csw > 0.f) newcnt += (atomicExch(&umask[n0 + 3], 1u) == 0u);
    if (ssx > 0.f) atomicAdd(&s1[n0 + 0], ssx);
    if (ssy > 0.f) atomicAdd(&s1[n0 + 1], ssy);
    if (ssz > 0.f) atomicAdd(&s1[n0 + 2], ssz);
    if (ssw > 0.f) atomicAdd(&s1[n0 + 3], ssw);
  }
#pragma unroll
  for (int off = 32; off; off >>= 1) newcnt += __shfl_down(newcnt, off);
  if ((threadIdx.x & 63) == 0 && newcnt) atomicAdd(&counters[0], newcnt);
}

// fused compaction + finalize: mlist (umask), vidx set as packed {n, log p1},
// p1 = s1/num_neis in place, sum_p1 partial
__global__ __launch_bounds__(256) void k_finfuse(float* __restrict__ s1p1,
                                                 const u32* __restrict__ umask,
                                                 int* __restrict__ mlist,
                                                 u64* __restrict__ vpack,
                                                 int* __restrict__ counters,
                                                 float* __restrict__ scal) {
  int n = blockIdx.x * 256 + threadIdx.x;
  bool on = (n < NN);
  int lane = threadIdx.x & 63;
  float nnf = (float)counters[0];
  {
    bool pred = on && (umask[on ? n : 0] != 0u);
    u64 bm = __ballot(pred);
    int cnt = __popcll(bm);
    if (cnt) {
      int leader = __ffsll((u64)bm) - 1;
      int base = 0;
      if (lane == leader) base = atomicAdd(&counters[2], cnt);
      base = __shfl(base, leader);
      if (pred) mlist[base + __popcll(bm & ((1ull << lane) - 1ull))] = n;
    }
  }
  float local = 0.0f;
  {
    float s = on ? s1p1[n] : 0.0f;
    bool pred = (s > 0.0f);
    u64 bm = __ballot(pred);
    int cnt = __popcll(bm);
    if (cnt) {
      int leader = __ffsll((u64)bm) - 1;
      int base = 0;
      if (lane == leader) base = atomicAdd(&counters[1], cnt);
      base = __shfl(base, leader);
      if (pred) {
        float p = s / nnf;
        s1p1[n] = p;
        local = p;
        float lp = logf(p);
        int j = base + __popcll(bm & ((1ull << lane) - 1ull));
        vpack[j] = ((u64)(u32)n << 32) | (u64)__float_as_uint(lp);
      }
    }
  }
#pragma unroll
  for (int off = 32; off; off >>= 1) local += __shfl_down(local, off);
  if (lane == 0 && local != 0.0f) atomicAdd(&scal[0], local);
}

// 4 blocks per sample: partial argmax over packed valid list, u64 atomicMax merge
__global__ __launch_bounds__(256) void k_sample(const u64* __restrict__ vpack,
                                                const int* __restrict__ counters,
                                                u64* __restrict__ slots) {
  __shared__ u64 sk[256];
  int s = blockIdx.x >> 2;
  int quarter = blockIdx.x & 3;
  int nv = counters[1];
  u64 best = 0ull;
  u32 base = (u32)s * (u32)NN;
  for (int j = quarter * 256 + threadIdx.x; j < nv; j += 1024) {
    u64 pk = vpack[j];
    int n = (int)(pk >> 32);
    float lp = __uint_as_float((u32)pk);
    uint2 r = tf2x32(0u, base + (u32)n);
    float g = gumbel_from_bits(r.x ^ r.y) + lp;
    u64 key = pack_key(g, n);
    if (key > best) best = key;
  }
  sk[threadIdx.x] = best;
  __syncthreads();
#pragma unroll
  for (int off = 128; off; off >>= 1) {
    if (threadIdx.x < off) {
      u64 o = sk[threadIdx.x + off];
      if (o > sk[threadIdx.x]) sk[threadIdx.x] = o;
    }
    __syncthreads();
  }
  if (threadIdx.x == 0) atomicMax(&slots[s], sk[0]);
}

// means[d] = sum over masked rows; wave-per-row float4, LDS pre-reduce
__global__ __launch_bounds__(256) void k_means(const float* __restrict__ feat,
                                               const int* __restrict__ mlist,
                                               const int* __restrict__ counters,
                                               float* __restrict__ means) {
  __shared__ float part[4][DD];
  int nm = counters[2];
  int wv = threadIdx.x >> 6;
  int lane = threadIdx.x & 63;
  int wave = blockIdx.x * 4 + wv;
  int stride = gridDim.x * 4;
  float4 acc = {0.f, 0.f, 0.f, 0.f};
  for (int j = wave; j < nm; j += stride) {
    float4 f = ((const float4*)(feat + (size_t)mlist[j] * DD))[lane];
    acc.x += f.x; acc.y += f.y; acc.z += f.z; acc.w += f.w;
  }
  ((float4*)part[wv])[lane] = acc;
  __syncthreads();
  int d = threadIdx.x;
  float vv = part[0][d] + part[1][d] + part[2][d] + part[3][d];
  atomicAdd(&means[d], vv);
}

// loss_acc = sum over valid rows of p_u * ||f[row]-means||^2 (wave per row)
__global__ void k_loss(const float* __restrict__ feat, const float* __restrict__ means,
                       const float* __restrict__ s1p1, const u64* __restrict__ vpack,
                       const int* __restrict__ counters, float* __restrict__ scal) {
  __shared__ float ms[DD];
  ms[threadIdx.x] = means[threadIdx.x];
  __syncthreads();
  int nv = counters[1];
  float spu = scal[0];
  int gw = blockIdx.x * 4 + (threadIdx.x >> 6);
  int tw = gridDim.x * 4;
  int lane = threadIdx.x & 63;
  float wacc = 0.0f;
  for (int j = gw; j < nv; j += tw) {
    int r = (int)(vpack[j] >> 32);
    float4 f4v = ((const float4*)(feat + (size_t)r * DD))[lane];
    float4 m4 = ((const float4*)ms)[lane];
    float dx = f4v.x - m4.x, dy = f4v.y - m4.y, dz = f4v.z - m4.z, dw = f4v.w - m4.w;
    float val = dx * dx + dy * dy + dz * dz + dw * dw;
#pragma unroll
    for (int off = 32; off; off >>= 1) val += __shfl_down(val, off);
    if (lane == 0) wacc += (s1p1[r] / spu) * val;
  }
  if (lane == 0) atomicAdd(&scal[1], wacc);
}

// fused epilogue: blocks 0..255 copy x_u rows; blocks 256..511 write support row b
__global__ __launch_bounds__(512) void k_tail(const float* __restrict__ feat,
                                              const float* __restrict__ adj,
                                              const float* __restrict__ s1p1,
                                              const u64* __restrict__ slots,
                                              const float* __restrict__ scal,
                                              float* __restrict__ out) {
  int blk = blockIdx.x;
  if (blk < 256) {
    int s = blk * 2 + (threadIdx.x >> 8);
    int t = threadIdx.x & 255;
    int idx = (int)(~(u32)slots[s]);
    out[(size_t)s * DD + t] = feat[(size_t)idx * DD + t];
  } else {
    int b = blk - 256;
    int s = threadIdx.x;  // 0..511
    int idx = (int)(~(u32)slots[s]);
    float denom = s1p1[idx] * (float)SS;
    out[(size_t)SS * DD + (size_t)b * SS + s] = adj[(size_t)b * NN + idx] / denom;
    if (b == 255 && s == 0) out[(size_t)SS * DD + (size_t)BB * SS] = scal[1] / (float)DD;
  }
}

extern "C" void kernel_launch(void* const* d_in, const int* in_sizes, int n_in,
                              void* d_out, int out_size, void* d_ws, size_t ws_size,
                              hipStream_t stream) {
  const float* feat = (const float*)d_in[0];
  const float* adj  = (const float*)d_in[1];
  const float* w1   = (const float*)d_in[2];
  const float* w2   = (const float*)d_in[3];
  const int*   v    = (const int*)d_in[4];
  float* out = (float*)d_out;

  float* ws    = (float*)d_ws;
  float* fw2   = ws;                             // [NN]
  float* s1p1  = ws + (size_t)NN;                // [NN] s1 then p1 in place
  u64*   vpack = (u64*)(ws + 2 * (size_t)NN);    // [NN] packed {n, log p1} (2NN floats)
  int*   mlist = (int*)(ws + 4 * (size_t)NN);    // [NN]
  u32*   umask = (u32*)(ws + 5 * (size_t)NN);    // [NN] words
  float* tail  = ws + 6 * (size_t)NN;
  float* hw1   = tail;                           // [256]
  float* means = tail + 256;                     // [256]
  float* scal  = tail + 512;                     // [16]: [0]=sum_p1 [1]=loss
  int*   counters = (int*)(scal + 2);            // [0]=num_neis [1]=nv [2]=nm
  u64*   slots = (u64*)(tail + 544);             // [512]

  k_front<<<FW_BLOCKS + 16, 256, 0, stream>>>(feat, w1, w2, v, fw2, hw1,
                                              s1p1, umask, means, scal, slots);
  k_adj_partial<<<196 * 8, 256, 0, stream>>>(adj, fw2, hw1, s1p1, umask, counters);
  k_finfuse<<<(NN + 255) / 256, 256, 0, stream>>>(s1p1, umask, mlist, vpack, counters, scal);
  k_sample<<<SS * 4, 256, 0, stream>>>(vpack, counters, slots);
  k_means<<<128, 256, 0, stream>>>(feat, mlist, counters, means);
  k_loss<<<256, 256, 0, stream>>>(feat, means, s1p1, vpack, counters, scal);
  k_tail<<<512, 512, 0, stream>>>(feat, adj, s1p1, slots, scal, out);
}

// Round 6
// 262.155 us; speedup vs baseline: 1.3140x; 1.3140x over previous
//
#include <hip/hip_runtime.h>
#include <math.h>
#include <stdint.h>

#define NN 200000   // nodes
#define NQ 50000    // NN/4 column quads
#define DD 256      // feature dim
#define BB 256      // batch rows of adj
#define SS 512      // output samples

// PRNG: threefry_partitionable: elem i -> tf(0, i), bits = out0 ^ out1
// (verified bit-exact PASS, absmax 0.0, rounds 2-5)
// NOTE (round 5 lesson): keep atomics OUT of the adj inner pass (atomicExch on
// umask) and do NOT bunch counter atomics into one fused kernel — both caused
// ~117 µs serialization stalls. Byte-store umask + separate compaction is fast.

typedef unsigned int u32;
typedef unsigned long long u64;
typedef float f4 __attribute__((ext_vector_type(4)));

__device__ __forceinline__ f4 ldnt4(const float* p) {
  return __builtin_nontemporal_load((const f4*)p);
}

// ---------------- threefry2x32, key = (0,1)  (jax.random.key(1)) ----------------
__device__ __forceinline__ uint2 tf2x32(u32 x0, u32 x1) {
  const u32 ks0 = 0u, ks1 = 1u, ks2 = 0x1BD11BDBu;
  x0 += ks0; x1 += ks1;
#define TFR(r) { x0 += x1; x1 = (x1 << (r)) | (x1 >> (32 - (r))); x1 ^= x0; }
  TFR(13) TFR(15) TFR(26) TFR(6)
  x0 += ks1; x1 += ks2 + 1u;
  TFR(17) TFR(29) TFR(16) TFR(24)
  x0 += ks2; x1 += ks0 + 2u;
  TFR(13) TFR(15) TFR(26) TFR(6)
  x0 += ks0; x1 += ks1 + 3u;
  TFR(17) TFR(29) TFR(16) TFR(24)
  x0 += ks1; x1 += ks2 + 4u;
  TFR(13) TFR(15) TFR(26) TFR(6)
  x0 += ks2; x1 += ks0 + 5u;
#undef TFR
  return make_uint2(x0, x1);
}

__device__ __forceinline__ float gumbel_from_bits(u32 bits) {
  const float TINY = 1.17549435e-38f;
  float f = __uint_as_float((bits >> 9) | 0x3f800000u) - 1.0f; // [0,1)
  float x = f + TINY;
  x = fmaxf(TINY, x);
  return -logf(-logf(x));
}

// pack (gumbel g, index n) so u64-max == (argmax g, first-index tie-break)
__device__ __forceinline__ u64 pack_key(float g, int n) {
  u32 u = __float_as_uint(g);
  u32 m = (u & 0x80000000u) ? ~u : (u | 0x80000000u); // monotone order-preserving map
  return ((u64)m << 32) | (u32)(~(u32)n);             // larger ~n == smaller n wins ties
}

// ---------------- kernels ----------------
// zero s1, umask words, means, scal/counters, sample slots
__global__ void k_zero(float* __restrict__ s1, u32* __restrict__ umaskw,
                       float* __restrict__ means, float* __restrict__ scal,
                       u64* __restrict__ slots) {
  int i = blockIdx.x * 256 + threadIdx.x;
  int stride = gridDim.x * 256;
  for (int j = i; j < NN; j += stride) s1[j] = 0.0f;
  for (int j = i; j < NQ; j += stride) umaskw[j] = 0u;
  if (i < 256) means[i] = 0.0f;
  if (i < 16) scal[i] = 0.0f;
  if (i < SS) slots[i] = 0ull;
}

// four rows per wave: dot(feat[row], w). rows==nullptr -> streaming (nontemporal feat)
__global__ __launch_bounds__(256) void k_dotw(const float* __restrict__ feat,
                                              const float* __restrict__ w,
                                              float* __restrict__ outv,
                                              const int* __restrict__ rows,
                                              int nrows) {
  int wave = blockIdx.x * 4 + (threadIdx.x >> 6);
  int lane = threadIdx.x & 63;
  int r0 = wave * 4;
  if (r0 >= nrows) return;  // nrows divisible by 4 in both uses
  f4 w4 = ((const f4*)w)[lane];
  f4 f[4];
  if (rows) {
#pragma unroll
    for (int k = 0; k < 4; ++k)
      f[k] = ((const f4*)(feat + (size_t)rows[r0 + k] * DD))[lane];
  } else {
#pragma unroll
    for (int k = 0; k < 4; ++k)
      f[k] = ldnt4(feat + (size_t)(r0 + k) * DD + lane * 4);
  }
  float d[4];
#pragma unroll
  for (int k = 0; k < 4; ++k)
    d[k] = f[k].x * w4.x + f[k].y * w4.y + f[k].z * w4.z + f[k].w * w4.w;
#pragma unroll
  for (int off = 32; off; off >>= 1) {
#pragma unroll
    for (int k = 0; k < 4; ++k) d[k] += __shfl_down(d[k], off);
  }
  if (lane == 0) {
#pragma unroll
    for (int k = 0; k < 4; ++k) outv[r0 + k] = d[k];
  }
}

// b-chunked column pass over adj: 8 chunks x 32 b. float4 columns, 8 loads in flight.
__global__ __launch_bounds__(256) void k_adj_partial(const float* __restrict__ adj,
                                                     const float* __restrict__ fw2,
                                                     const float* __restrict__ hw1,
                                                     float* __restrict__ s1,
                                                     unsigned char* __restrict__ umask) {
  __shared__ float hs[BB];
  hs[threadIdx.x] = hw1[threadIdx.x];
  __syncthreads();
  int cb = blockIdx.x % 196;  // column block (1024 cols each)
  int ch = blockIdx.x / 196;  // b-chunk 0..7 (32 b each)
  int q = cb * 256 + threadIdx.x;
  if (q >= NQ) return;
  const float4* adj4 = (const float4*)adj;
  float4 fv = ((const float4*)fw2)[q];
  float csx = 0.f, csy = 0.f, csz = 0.f, csw = 0.f;
  float ssx = 0.f, ssy = 0.f, ssz = 0.f, ssw = 0.f;
  int b0 = ch * 32;
  for (int bb = 0; bb < 32; bb += 8) {
    float4 a[8];
#pragma unroll
    for (int k = 0; k < 8; ++k) a[k] = adj4[(size_t)(b0 + bb + k) * NQ + q];
#pragma unroll
    for (int k = 0; k < 8; ++k) {
      float h = hs[b0 + bb + k] + 1.0f;
      csx += a[k].x; csy += a[k].y; csz += a[k].z; csw += a[k].w;
      ssx += a[k].x * fmaxf(h + fv.x, 0.f);
      ssy += a[k].y * fmaxf(h + fv.y, 0.f);
      ssz += a[k].z * fmaxf(h + fv.z, 0.f);
      ssw += a[k].w * fmaxf(h + fv.w, 0.f);
    }
  }
  int n0 = q * 4;
  if (csx > 0.f) umask[n0 + 0] = 1;
  if (csy > 0.f) umask[n0 + 1] = 1;
  if (csz > 0.f) umask[n0 + 2] = 1;
  if (csw > 0.f) umask[n0 + 3] = 1;
  if (ssx > 0.f) atomicAdd(&s1[n0 + 0], ssx);
  if (ssy > 0.f) atomicAdd(&s1[n0 + 1], ssy);
  if (ssz > 0.f) atomicAdd(&s1[n0 + 2], ssz);
  if (ssw > 0.f) atomicAdd(&s1[n0 + 3], ssw);
}

// build compacted mask list (umask) and valid list (s1>0) + counts
__global__ __launch_bounds__(256) void k_adj_fin(const float* __restrict__ s1,
                                                 const unsigned char* __restrict__ umask,
                                                 int* __restrict__ mlist,
                                                 int* __restrict__ vidx,
                                                 int* __restrict__ counters) {
  int n = blockIdx.x * 256 + threadIdx.x;
  bool on = (n < NN);
  int lane = threadIdx.x & 63;
  {
    bool pred = on && (umask[on ? n : 0] != 0);
    u64 bm = __ballot(pred);
    int cnt = __popcll(bm);
    if (cnt) {
      int leader = __ffsll((u64)bm) - 1;
      int base = 0;
      if (lane == leader) base = atomicAdd(&counters[0], cnt);
      base = __shfl(base, leader);
      if (pred) mlist[base + __popcll(bm & ((1ull << lane) - 1ull))] = n;
    }
  }
  {
    bool pred = on && (s1[on ? n : 0] > 0.0f);
    u64 bm = __ballot(pred);
    int cnt = __popcll(bm);
    if (cnt) {
      int leader = __ffsll((u64)bm) - 1;
      int base = 0;
      if (lane == leader) base = atomicAdd(&counters[1], cnt);
      base = __shfl(base, leader);
      if (pred) vidx[base + __popcll(bm & ((1ull << lane) - 1ull))] = n;
    }
  }
}

// p1 = s1/num_neis (in place), vlog[j] = log(p1), sum_p1
__global__ void k_fin(float* __restrict__ s1p1, float* __restrict__ vlog,
                      const int* __restrict__ vidx, const int* __restrict__ counters,
                      float* __restrict__ scal) {
  int nv = counters[1];
  float nnf = (float)counters[0];
  float local = 0.0f;
  for (int j = blockIdx.x * blockDim.x + threadIdx.x; j < nv; j += gridDim.x * blockDim.x) {
    int n = vidx[j];
    float p = s1p1[n] / nnf;
    s1p1[n] = p;
    vlog[j] = logf(p);
    local += p;
  }
#pragma unroll
  for (int off = 32; off; off >>= 1) local += __shfl_down(local, off);
  if ((threadIdx.x & 63) == 0) atomicAdd(&scal[0], local);
}

// 4 blocks per sample: partial argmax over valid list, u64 atomicMax merge
__global__ __launch_bounds__(256) void k_sample(const int* __restrict__ vidx,
                                                const float* __restrict__ vlog,
                                                const int* __restrict__ counters,
                                                u64* __restrict__ slots) {
  __shared__ u64 sk[256];
  int s = blockIdx.x >> 2;
  int quarter = blockIdx.x & 3;
  int nv = counters[1];
  u64 best = 0ull;
  u32 base = (u32)s * (u32)NN;
#pragma unroll 2
  for (int j = quarter * 256 + threadIdx.x; j < nv; j += 1024) {
    int n = vidx[j];
    uint2 r = tf2x32(0u, base + (u32)n);
    float g = gumbel_from_bits(r.x ^ r.y) + vlog[j];
    u64 key = pack_key(g, n);
    if (key > best) best = key;
  }
  sk[threadIdx.x] = best;
  __syncthreads();
#pragma unroll
  for (int off = 128; off; off >>= 1) {
    if (threadIdx.x < off) {
      u64 o = sk[threadIdx.x + off];
      if (o > sk[threadIdx.x]) sk[threadIdx.x] = o;
    }
    __syncthreads();
  }
  if (threadIdx.x == 0) atomicMax(&slots[s], sk[0]);
}

// means[d] = sum over masked rows; wave-per-row float4, LDS pre-reduce
__global__ __launch_bounds__(256) void k_means(const float* __restrict__ feat,
                                               const int* __restrict__ mlist,
                                               const int* __restrict__ counters,
                                               float* __restrict__ means) {
  __shared__ float part[4][DD];
  int nm = counters[0];
  int wv = threadIdx.x >> 6;
  int lane = threadIdx.x & 63;
  int wave = blockIdx.x * 4 + wv;
  int stride = gridDim.x * 4;
  float4 acc = {0.f, 0.f, 0.f, 0.f};
  for (int j = wave; j < nm; j += stride) {
    float4 f = ((const float4*)(feat + (size_t)mlist[j] * DD))[lane];
    acc.x += f.x; acc.y += f.y; acc.z += f.z; acc.w += f.w;
  }
  ((float4*)part[wv])[lane] = acc;
  __syncthreads();
  int d = threadIdx.x;
  float v = part[0][d] + part[1][d] + part[2][d] + part[3][d];
  atomicAdd(&means[d], v);
}

// loss_acc = sum over valid rows of p_u * ||f[row]-means||^2 (wave per row)
__global__ void k_loss(const float* __restrict__ feat, const float* __restrict__ means,
                       const float* __restrict__ s1p1, const int* __restrict__ vidx,
                       const int* __restrict__ counters, float* __restrict__ scal) {
  __shared__ float ms[DD];
  ms[threadIdx.x] = means[threadIdx.x];
  __syncthreads();
  int nv = counters[1];
  float spu = scal[0];
  int gw = blockIdx.x * 4 + (threadIdx.x >> 6);
  int tw = gridDim.x * 4;
  int lane = threadIdx.x & 63;
  float wacc = 0.0f;
  for (int j = gw; j < nv; j += tw) {
    int r = vidx[j];
    float4 f4v = ((const float4*)(feat + (size_t)r * DD))[lane];
    float4 m4 = ((const float4*)ms)[lane];
    float dx = f4v.x - m4.x, dy = f4v.y - m4.y, dz = f4v.z - m4.z, dw = f4v.w - m4.w;
    float val = dx * dx + dy * dy + dz * dz + dw * dw;
#pragma unroll
    for (int off = 32; off; off >>= 1) val += __shfl_down(val, off);
    if (lane == 0) wacc += (s1p1[r] / spu) * val;
  }
  if (lane == 0) atomicAdd(&scal[1], wacc);
}

// fused epilogue: blocks 0..255 copy x_u rows (2 samples each);
// blocks 256..511 write support row b (coalesced), gathering adj from L3
__global__ __launch_bounds__(512) void k_tail(const float* __restrict__ feat,
                                              const float* __restrict__ adj,
                                              const float* __restrict__ s1p1,
                                              const u64* __restrict__ slots,
                                              const float* __restrict__ scal,
                                              float* __restrict__ out) {
  int blk = blockIdx.x;
  if (blk < 256) {
    int s = blk * 2 + (threadIdx.x >> 8);
    int t = threadIdx.x & 255;
    int idx = (int)(~(u32)slots[s]);
    out[(size_t)s * DD + t] = feat[(size_t)idx * DD + t];
  } else {
    int b = blk - 256;
    int s = threadIdx.x;  // 0..511
    int idx = (int)(~(u32)slots[s]);
    float denom = s1p1[idx] * (float)SS;
    out[(size_t)SS * DD + (size_t)b * SS + s] = adj[(size_t)b * NN + idx] / denom;
    if (b == 255 && s == 0) out[(size_t)SS * DD + (size_t)BB * SS] = scal[1] / (float)DD;
  }
}

extern "C" void kernel_launch(void* const* d_in, const int* in_sizes, int n_in,
                              void* d_out, int out_size, void* d_ws, size_t ws_size,
                              hipStream_t stream) {
  const float* feat = (const float*)d_in[0];
  const float* adj  = (const float*)d_in[1];
  const float* w1   = (const float*)d_in[2];
  const float* w2   = (const float*)d_in[3];
  const int*   v    = (const int*)d_in[4];
  float* out = (float*)d_out;

  float* ws    = (float*)d_ws;
  float* fw2   = ws;                          // [NN]
  float* s1p1  = ws + (size_t)NN;             // [NN] s1 then p1 in place
  float* vlog  = ws + 2 * (size_t)NN;         // [NN]
  int*   vidx  = (int*)(ws + 3 * (size_t)NN); // [NN]
  int*   mlist = (int*)(ws + 4 * (size_t)NN); // [NN]
  unsigned char* umask = (unsigned char*)(ws + 5 * (size_t)NN); // [NN] bytes
  float* tail  = ws + 5 * (size_t)NN + NQ;
  float* hw1   = tail;                        // [256]
  float* means = tail + 256;                  // [256]
  float* scal  = tail + 512;                  // [16]: [0]=sum_p1 [1]=loss; ints at +2
  int*   counters = (int*)(scal + 2);         // [0]=n_mask [1]=n_valid
  u64*   slots = (u64*)(tail + 544);          // [512] u64 argmax slots (8B aligned)

  k_zero<<<512, 256, 0, stream>>>(s1p1, (u32*)umask, means, scal, slots);
  k_dotw<<<NN / 16, 256, 0, stream>>>(feat, w2, fw2, nullptr, NN);
  k_dotw<<<BB / 16, 256, 0, stream>>>(feat, w1, hw1, v, BB);
  k_adj_partial<<<196 * 8, 256, 0, stream>>>(adj, fw2, hw1, s1p1, umask);
  k_adj_fin<<<(NN + 255) / 256, 256, 0, stream>>>(s1p1, umask, mlist, vidx, counters);
  k_fin<<<128, 256, 0, stream>>>(s1p1, vlog, vidx, counters, scal);
  k_sample<<<SS * 4, 256, 0, stream>>>(vidx, vlog, counters, slots);
  k_means<<<128, 256, 0, stream>>>(feat, mlist, counters, means);
  k_loss<<<256, 256, 0, stream>>>(feat, means, s1p1, vidx, counters, scal);
  k_tail<<<512, 512, 0, stream>>>(feat, adj, s1p1, slots, scal, out);
}

// Round 7
// 248.798 us; speedup vs baseline: 1.3845x; 1.0537x over previous
//
#include <hip/hip_runtime.h>
#include <math.h>
#include <stdint.h>

#define NN 200000   // nodes
#define NQ 50000    // NN/4 column quads
#define DD 256      // feature dim
#define BB 256      // batch rows of adj
#define SS 512      // output samples
#define FW_BLOCKS 12500  // NN/16 rows-per-block for the fw2 stream
#define QB 196      // ceil(NQ/256) column blocks
#define NCH 16      // b-chunks (16 b each)

// PRNG: threefry_partitionable: elem i -> tf(0, i), bits = out0 ^ out1
// (verified bit-exact PASS, absmax 0.0, rounds 2-6)
// Round-5 lesson: NO RMW atomics (atomicExch) in bulk passes, no bunched
// counter atomics in fused compaction. Byte-store umask + sparse atomicAdd ok.

typedef unsigned int u32;
typedef unsigned long long u64;
typedef float f4 __attribute__((ext_vector_type(4)));

__device__ __forceinline__ f4 ldnt4(const float* p) {
  return __builtin_nontemporal_load((const f4*)p);
}

// ---------------- threefry2x32, key = (0,1)  (jax.random.key(1)) ----------------
__device__ __forceinline__ uint2 tf2x32(u32 x0, u32 x1) {
  const u32 ks0 = 0u, ks1 = 1u, ks2 = 0x1BD11BDBu;
  x0 += ks0; x1 += ks1;
#define TFR(r) { x0 += x1; x1 = (x1 << (r)) | (x1 >> (32 - (r))); x1 ^= x0; }
  TFR(13) TFR(15) TFR(26) TFR(6)
  x0 += ks1; x1 += ks2 + 1u;
  TFR(17) TFR(29) TFR(16) TFR(24)
  x0 += ks2; x1 += ks0 + 2u;
  TFR(13) TFR(15) TFR(26) TFR(6)
  x0 += ks0; x1 += ks1 + 3u;
  TFR(17) TFR(29) TFR(16) TFR(24)
  x0 += ks1; x1 += ks2 + 4u;
  TFR(13) TFR(15) TFR(26) TFR(6)
  x0 += ks2; x1 += ks0 + 5u;
#undef TFR
  return make_uint2(x0, x1);
}

__device__ __forceinline__ float gumbel_from_bits(u32 bits) {
  const float TINY = 1.17549435e-38f;
  float f = __uint_as_float((bits >> 9) | 0x3f800000u) - 1.0f; // [0,1)
  float x = f + TINY;
  x = fmaxf(TINY, x);
  return -logf(-logf(x));
}

// pack (gumbel g, index n) so u64-max == (argmax g, first-index tie-break)
__device__ __forceinline__ u64 pack_key(float g, int n) {
  u32 u = __float_as_uint(g);
  u32 m = (u & 0x80000000u) ? ~u : (u | 0x80000000u);
  return ((u64)m << 32) | (u32)(~(u32)n);
}

// ---------------- kernels ----------------
// fused front: blocks <FW_BLOCKS stream fw2 = feat@w2 (nontemporal); last 16
// blocks compute hw1 = feat[v]@w1; first 512 blocks also zero scratch.
__global__ __launch_bounds__(256) void k_front(const float* __restrict__ feat,
                                               const float* __restrict__ w1,
                                               const float* __restrict__ w2,
                                               const int* __restrict__ v,
                                               float* __restrict__ fw2,
                                               float* __restrict__ hw1,
                                               float* __restrict__ s1,
                                               u32* __restrict__ umaskw,
                                               float* __restrict__ means,
                                               float* __restrict__ scal,
                                               u64* __restrict__ slots) {
  int blk = blockIdx.x;
  int wv = threadIdx.x >> 6;
  int lane = threadIdx.x & 63;
  if (blk < FW_BLOCKS) {
    int r0 = (blk * 4 + wv) * 4;
    f4 w4 = ((const f4*)w2)[lane];
    f4 f[4];
#pragma unroll
    for (int k = 0; k < 4; ++k)
      f[k] = ldnt4(feat + (size_t)(r0 + k) * DD + lane * 4);
    float d[4];
#pragma unroll
    for (int k = 0; k < 4; ++k)
      d[k] = f[k].x * w4.x + f[k].y * w4.y + f[k].z * w4.z + f[k].w * w4.w;
#pragma unroll
    for (int off = 32; off; off >>= 1) {
#pragma unroll
      for (int k = 0; k < 4; ++k) d[k] += __shfl_down(d[k], off);
    }
    if (lane == 0) {
#pragma unroll
      for (int k = 0; k < 4; ++k) fw2[r0 + k] = d[k];
    }
    if (blk < 512) {
      int i = blk * 256 + threadIdx.x;
      for (int j = i; j < NN; j += 512 * 256) s1[j] = 0.0f;
      for (int j = i; j < NQ; j += 512 * 256) umaskw[j] = 0u;
      if (i < 256) means[i] = 0.0f;
      if (i < 16) scal[i] = 0.0f;
      if (i < SS) slots[i] = 0ull;
    }
  } else {
    int r0 = ((blk - FW_BLOCKS) * 4 + wv) * 4;  // rows 0..255
    f4 w4 = ((const f4*)w1)[lane];
    f4 f[4];
#pragma unroll
    for (int k = 0; k < 4; ++k)
      f[k] = ((const f4*)(feat + (size_t)v[r0 + k] * DD))[lane];
    float d[4];
#pragma unroll
    for (int k = 0; k < 4; ++k)
      d[k] = f[k].x * w4.x + f[k].y * w4.y + f[k].z * w4.z + f[k].w * w4.w;
#pragma unroll
    for (int off = 32; off; off >>= 1) {
#pragma unroll
      for (int k = 0; k < 4; ++k) d[k] += __shfl_down(d[k], off);
    }
    if (lane == 0) {
#pragma unroll
      for (int k = 0; k < 4; ++k) hw1[r0 + k] = d[k];
    }
  }
}

// b-chunked column pass over adj: 16 chunks x 16 b, float4 columns, 4-deep load
// batches. Lower VGPR + 3136 blocks -> high occupancy, BW-bound cold read.
__global__ __launch_bounds__(256) void k_adj_partial(const float* __restrict__ adj,
                                                     const float* __restrict__ fw2,
                                                     const float* __restrict__ hw1,
                                                     float* __restrict__ s1,
                                                     unsigned char* __restrict__ umask) {
  __shared__ float hs[16];
  int cb = blockIdx.x % QB;   // column block (1024 cols each)
  int ch = blockIdx.x / QB;   // b-chunk 0..15 (16 b each)
  int b0 = ch * 16;
  if (threadIdx.x < 16) hs[threadIdx.x] = hw1[b0 + threadIdx.x] + 1.0f;
  __syncthreads();
  int q = cb * 256 + threadIdx.x;
  if (q >= NQ) return;
  const float4* adj4 = (const float4*)adj;
  float4 fv = ((const float4*)fw2)[q];
  float csx = 0.f, csy = 0.f, csz = 0.f, csw = 0.f;
  float ssx = 0.f, ssy = 0.f, ssz = 0.f, ssw = 0.f;
  for (int bb = 0; bb < 16; bb += 4) {
    float4 a[4];
#pragma unroll
    for (int k = 0; k < 4; ++k) a[k] = adj4[(size_t)(b0 + bb + k) * NQ + q];
#pragma unroll
    for (int k = 0; k < 4; ++k) {
      float h = hs[bb + k];
      csx += a[k].x; csy += a[k].y; csz += a[k].z; csw += a[k].w;
      ssx += a[k].x * fmaxf(h + fv.x, 0.f);
      ssy += a[k].y * fmaxf(h + fv.y, 0.f);
      ssz += a[k].z * fmaxf(h + fv.z, 0.f);
      ssw += a[k].w * fmaxf(h + fv.w, 0.f);
    }
  }
  int n0 = q * 4;
  if (csx > 0.f) umask[n0 + 0] = 1;
  if (csy > 0.f) umask[n0 + 1] = 1;
  if (csz > 0.f) umask[n0 + 2] = 1;
  if (csw > 0.f) umask[n0 + 3] = 1;
  if (ssx > 0.f) atomicAdd(&s1[n0 + 0], ssx);
  if (ssy > 0.f) atomicAdd(&s1[n0 + 1], ssy);
  if (ssz > 0.f) atomicAdd(&s1[n0 + 2], ssz);
  if (ssw > 0.f) atomicAdd(&s1[n0 + 3], ssw);
}

// build compacted mask list (umask) and valid list (s1>0) + counts
__global__ __launch_bounds__(256) void k_adj_fin(const float* __restrict__ s1,
                                                 const unsigned char* __restrict__ umask,
                                                 int* __restrict__ mlist,
                                                 int* __restrict__ vidx,
                                                 int* __restrict__ counters) {
  int n = blockIdx.x * 256 + threadIdx.x;
  bool on = (n < NN);
  int lane = threadIdx.x & 63;
  {
    bool pred = on && (umask[on ? n : 0] != 0);
    u64 bm = __ballot(pred);
    int cnt = __popcll(bm);
    if (cnt) {
      int leader = __ffsll((u64)bm) - 1;
      int base = 0;
      if (lane == leader) base = atomicAdd(&counters[0], cnt);
      base = __shfl(base, leader);
      if (pred) mlist[base + __popcll(bm & ((1ull << lane) - 1ull))] = n;
    }
  }
  {
    bool pred = on && (s1[on ? n : 0] > 0.0f);
    u64 bm = __ballot(pred);
    int cnt = __popcll(bm);
    if (cnt) {
      int leader = __ffsll((u64)bm) - 1;
      int base = 0;
      if (lane == leader) base = atomicAdd(&counters[1], cnt);
      base = __shfl(base, leader);
      if (pred) vidx[base + __popcll(bm & ((1ull << lane) - 1ull))] = n;
    }
  }
}

// p1 = s1/num_neis (in place), vlog[j] = log(p1), sum_p1
__global__ void k_fin(float* __restrict__ s1p1, float* __restrict__ vlog,
                      const int* __restrict__ vidx, const int* __restrict__ counters,
                      float* __restrict__ scal) {
  int nv = counters[1];
  float nnf = (float)counters[0];
  float local = 0.0f;
  for (int j = blockIdx.x * blockDim.x + threadIdx.x; j < nv; j += gridDim.x * blockDim.x) {
    int n = vidx[j];
    float p = s1p1[n] / nnf;
    s1p1[n] = p;
    vlog[j] = logf(p);
    local += p;
  }
#pragma unroll
  for (int off = 32; off; off >>= 1) local += __shfl_down(local, off);
  if ((threadIdx.x & 63) == 0) atomicAdd(&scal[0], local);
}

// heterogeneous: blocks 0..2047 = sample argmax (4 blocks/sample, VALU-bound);
// blocks 2048..2175 = means gather (memory-bound). Both ready after k_fin.
__global__ __launch_bounds__(256) void k_mix(const int* __restrict__ vidx,
                                             const float* __restrict__ vlog,
                                             const int* __restrict__ counters,
                                             u64* __restrict__ slots,
                                             const float* __restrict__ feat,
                                             const int* __restrict__ mlist,
                                             float* __restrict__ means) {
  __shared__ u64 sk[256];
  __shared__ float part[4][DD];
  int blk = blockIdx.x;
  if (blk < SS * 4) {
    int s = blk >> 2;
    int quarter = blk & 3;
    int nv = counters[1];
    u64 best = 0ull;
    u32 base = (u32)s * (u32)NN;
#pragma unroll 2
    for (int j = quarter * 256 + threadIdx.x; j < nv; j += 1024) {
      int n = vidx[j];
      uint2 r = tf2x32(0u, base + (u32)n);
      float g = gumbel_from_bits(r.x ^ r.y) + vlog[j];
      u64 key = pack_key(g, n);
      if (key > best) best = key;
    }
    sk[threadIdx.x] = best;
    __syncthreads();
#pragma unroll
    for (int off = 128; off; off >>= 1) {
      if (threadIdx.x < off) {
        u64 o = sk[threadIdx.x + off];
        if (o > sk[threadIdx.x]) sk[threadIdx.x] = o;
      }
      __syncthreads();
    }
    if (threadIdx.x == 0) atomicMax(&slots[s], sk[0]);
  } else {
    int nm = counters[0];
    int wv = threadIdx.x >> 6;
    int lane = threadIdx.x & 63;
    int wave = (blk - SS * 4) * 4 + wv;
    int stride = 128 * 4;
    float4 acc = {0.f, 0.f, 0.f, 0.f};
    for (int j = wave; j < nm; j += stride) {
      float4 f = ((const float4*)(feat + (size_t)mlist[j] * DD))[lane];
      acc.x += f.x; acc.y += f.y; acc.z += f.z; acc.w += f.w;
    }
    ((float4*)part[wv])[lane] = acc;
    __syncthreads();
    int d = threadIdx.x;
    float vv = part[0][d] + part[1][d] + part[2][d] + part[3][d];
    atomicAdd(&means[d], vv);
  }
}

// loss_acc = sum over valid rows of p_u * ||f[row]-means||^2 (wave per row)
__global__ void k_loss(const float* __restrict__ feat, const float* __restrict__ means,
                       const float* __restrict__ s1p1, const int* __restrict__ vidx,
                       const int* __restrict__ counters, float* __restrict__ scal) {
  __shared__ float ms[DD];
  ms[threadIdx.x] = means[threadIdx.x];
  __syncthreads();
  int nv = counters[1];
  float spu = scal[0];
  int gw = blockIdx.x * 4 + (threadIdx.x >> 6);
  int tw = gridDim.x * 4;
  int lane = threadIdx.x & 63;
  float wacc = 0.0f;
  for (int j = gw; j < nv; j += tw) {
    int r = vidx[j];
    float4 f4v = ((const float4*)(feat + (size_t)r * DD))[lane];
    float4 m4 = ((const float4*)ms)[lane];
    float dx = f4v.x - m4.x, dy = f4v.y - m4.y, dz = f4v.z - m4.z, dw = f4v.w - m4.w;
    float val = dx * dx + dy * dy + dz * dz + dw * dw;
#pragma unroll
    for (int off = 32; off; off >>= 1) val += __shfl_down(val, off);
    if (lane == 0) wacc += (s1p1[r] / spu) * val;
  }
  if (lane == 0) atomicAdd(&scal[1], wacc);
}

// fused epilogue: blocks 0..255 copy x_u rows (2 samples each);
// blocks 256..511 write support row b (coalesced), gathering adj
__global__ __launch_bounds__(512) void k_tail(const float* __restrict__ feat,
                                              const float* __restrict__ adj,
                                              const float* __restrict__ s1p1,
                                              const u64* __restrict__ slots,
                                              const float* __restrict__ scal,
                                              float* __restrict__ out) {
  int blk = blockIdx.x;
  if (blk < 256) {
    int s = blk * 2 + (threadIdx.x >> 8);
    int t = threadIdx.x & 255;
    int idx = (int)(~(u32)slots[s]);
    out[(size_t)s * DD + t] = feat[(size_t)idx * DD + t];
  } else {
    int b = blk - 256;
    int s = threadIdx.x;  // 0..511
    int idx = (int)(~(u32)slots[s]);
    float denom = s1p1[idx] * (float)SS;
    out[(size_t)SS * DD + (size_t)b * SS + s] = adj[(size_t)b * NN + idx] / denom;
    if (b == 255 && s == 0) out[(size_t)SS * DD + (size_t)BB * SS] = scal[1] / (float)DD;
  }
}

extern "C" void kernel_launch(void* const* d_in, const int* in_sizes, int n_in,
                              void* d_out, int out_size, void* d_ws, size_t ws_size,
                              hipStream_t stream) {
  const float* feat = (const float*)d_in[0];
  const float* adj  = (const float*)d_in[1];
  const float* w1   = (const float*)d_in[2];
  const float* w2   = (const float*)d_in[3];
  const int*   v    = (const int*)d_in[4];
  float* out = (float*)d_out;

  float* ws    = (float*)d_ws;
  float* fw2   = ws;                          // [NN]
  float* s1p1  = ws + (size_t)NN;             // [NN] s1 then p1 in place
  float* vlog  = ws + 2 * (size_t)NN;         // [NN]
  int*   vidx  = (int*)(ws + 3 * (size_t)NN); // [NN]
  int*   mlist = (int*)(ws + 4 * (size_t)NN); // [NN]
  unsigned char* umask = (unsigned char*)(ws + 5 * (size_t)NN); // [NN] bytes
  float* tail  = ws + 5 * (size_t)NN + NQ;
  float* hw1   = tail;                        // [256]
  float* means = tail + 256;                  // [256]
  float* scal  = tail + 512;                  // [16]: [0]=sum_p1 [1]=loss; ints at +2
  int*   counters = (int*)(scal + 2);         // [0]=n_mask [1]=n_valid
  u64*   slots = (u64*)(tail + 544);          // [512]

  k_front<<<FW_BLOCKS + 16, 256, 0, stream>>>(feat, w1, w2, v, fw2, hw1,
                                              s1p1, (u32*)umask, means, scal, slots);
  k_adj_partial<<<QB * NCH, 256, 0, stream>>>(adj, fw2, hw1, s1p1, umask);
  k_adj_fin<<<(NN + 255) / 256, 256, 0, stream>>>(s1p1, umask, mlist, vidx, counters);
  k_fin<<<128, 256, 0, stream>>>(s1p1, vlog, vidx, counters, scal);
  k_mix<<<SS * 4 + 128, 256, 0, stream>>>(vidx, vlog, counters, slots, feat, mlist, means);
  k_loss<<<256, 256, 0, stream>>>(feat, means, s1p1, vidx, counters, scal);
  k_tail<<<512, 512, 0, stream>>>(feat, adj, s1p1, slots, scal, out);
}

// Round 8
// 200.587 us; speedup vs baseline: 1.7173x; 1.2403x over previous
//
#include <hip/hip_runtime.h>
#include <math.h>
#include <stdint.h>

#define NN 200000   // nodes
#define NQ 50000    // NN/4 column quads
#define DD 256      // feature dim
#define BB 256      // batch rows of adj
#define SS 512      // output samples
#define QB 196      // ceil(NQ/256) column blocks
#define NCH 16      // b-chunks (16 b each)
#define TCAP 1024   // per-block LDS triplet cap (mean 8.2/block)
#define TMAX (1u<<20) // global triplet buffer entries (mean 25.6K, 6000 sigma)

// PRNG: threefry_partitionable: elem i -> tf(0, i), bits = out0 ^ out1
// (verified bit-exact PASS, absmax 0.0, rounds 2-7)
// Round-5 lesson: no RMW atomics in bulk passes; byte-store umask + sparse
// atomicAdd + one LDS-staged global-atomic append per block are fine.

typedef unsigned int u32;
typedef unsigned long long u64;
typedef float f4 __attribute__((ext_vector_type(4)));

// ---------------- threefry2x32, key = (0,1)  (jax.random.key(1)) ----------------
__device__ __forceinline__ uint2 tf2x32(u32 x0, u32 x1) {
  const u32 ks0 = 0u, ks1 = 1u, ks2 = 0x1BD11BDBu;
  x0 += ks0; x1 += ks1;
#define TFR(r) { x0 += x1; x1 = (x1 << (r)) | (x1 >> (32 - (r))); x1 ^= x0; }
  TFR(13) TFR(15) TFR(26) TFR(6)
  x0 += ks1; x1 += ks2 + 1u;
  TFR(17) TFR(29) TFR(16) TFR(24)
  x0 += ks2; x1 += ks0 + 2u;
  TFR(13) TFR(15) TFR(26) TFR(6)
  x0 += ks0; x1 += ks1 + 3u;
  TFR(17) TFR(29) TFR(16) TFR(24)
  x0 += ks1; x1 += ks2 + 4u;
  TFR(13) TFR(15) TFR(26) TFR(6)
  x0 += ks2; x1 += ks0 + 5u;
#undef TFR
  return make_uint2(x0, x1);
}

__device__ __forceinline__ float gumbel_from_bits(u32 bits) {
  const float TINY = 1.17549435e-38f;
  float f = __uint_as_float((bits >> 9) | 0x3f800000u) - 1.0f; // [0,1)
  float x = f + TINY;
  x = fmaxf(TINY, x);
  return -logf(-logf(x));
}

// pack (gumbel g, index n) so u64-max == (argmax g, first-index tie-break)
__device__ __forceinline__ u64 pack_key(float g, int n) {
  u32 u = __float_as_uint(g);
  u32 m = (u & 0x80000000u) ? ~u : (u | 0x80000000u);
  return ((u64)m << 32) | (u32)(~(u32)n);
}

// ---------------- kernels ----------------
// k_pre: blocks 0..511 zero scratch; blocks 512..527 compute hw1 = feat[v]@w1
__global__ __launch_bounds__(256) void k_pre(const float* __restrict__ feat,
                                             const float* __restrict__ w1,
                                             const int* __restrict__ v,
                                             float* __restrict__ hw1,
                                             float* __restrict__ s1,
                                             u32* __restrict__ umaskw,
                                             float* __restrict__ means,
                                             float* __restrict__ scal,
                                             u64* __restrict__ slots) {
  int blk = blockIdx.x;
  if (blk < 512) {
    int i = blk * 256 + threadIdx.x;
    for (int j = i; j < NN; j += 512 * 256) s1[j] = 0.0f;
    for (int j = i; j < NQ; j += 512 * 256) umaskw[j] = 0u;
    if (i < 256) means[i] = 0.0f;
    if (i < 16) scal[i] = 0.0f;
    if (i < SS) slots[i] = 0ull;
  } else {
    int wv = threadIdx.x >> 6;
    int lane = threadIdx.x & 63;
    int r0 = ((blk - 512) * 4 + wv) * 4;  // rows 0..255
    f4 w4 = ((const f4*)w1)[lane];
    f4 f[4];
#pragma unroll
    for (int k = 0; k < 4; ++k)
      f[k] = ((const f4*)(feat + (size_t)v[r0 + k] * DD))[lane];
    float d[4];
#pragma unroll
    for (int k = 0; k < 4; ++k)
      d[k] = f[k].x * w4.x + f[k].y * w4.y + f[k].z * w4.z + f[k].w * w4.w;
#pragma unroll
    for (int off = 32; off; off >>= 1) {
#pragma unroll
      for (int k = 0; k < 4; ++k) d[k] += __shfl_down(d[k], off);
    }
    if (lane == 0) {
#pragma unroll
      for (int k = 0; k < 4; ++k) hw1[r0 + k] = d[k];
    }
  }
}

// single BW-bound pass over adj: col_sum partials -> umask bytes; sparse
// triplets {n,b,a} appended via LDS staging + one global atomic per block.
// Needs neither fw2 nor hw1.
__global__ __launch_bounds__(256) void k_adj_pass(const float* __restrict__ adj,
                                                  unsigned char* __restrict__ umask,
                                                  u64* __restrict__ trip,
                                                  int* __restrict__ counters) {
  __shared__ u32 cnt, gbase;
  __shared__ u64 buf[TCAP];
  if (threadIdx.x == 0) cnt = 0u;
  __syncthreads();
  int cb = blockIdx.x % QB;   // column block (1024 cols)
  int ch = blockIdx.x / QB;   // b-chunk 0..15 (16 b each)
  int b0 = ch * 16;
  int q = cb * 256 + threadIdx.x;
  if (q < NQ) {
    const float4* adj4 = (const float4*)adj;
    float csx = 0.f, csy = 0.f, csz = 0.f, csw = 0.f;
    u32 n0 = (u32)q * 4u;
    for (int bb = 0; bb < 16; bb += 4) {
      float4 a[4];
#pragma unroll
      for (int k = 0; k < 4; ++k) a[k] = adj4[(size_t)(b0 + bb + k) * NQ + q];
#pragma unroll
      for (int k = 0; k < 4; ++k) {
        u32 b = (u32)(b0 + bb + k);
        csx += a[k].x; csy += a[k].y; csz += a[k].z; csw += a[k].w;
        if (a[k].x > 0.f) { u32 s = atomicAdd(&cnt, 1u); if (s < TCAP) buf[s] = ((u64)(((n0 + 0u) << 8) | b) << 32) | __float_as_uint(a[k].x); }
        if (a[k].y > 0.f) { u32 s = atomicAdd(&cnt, 1u); if (s < TCAP) buf[s] = ((u64)(((n0 + 1u) << 8) | b) << 32) | __float_as_uint(a[k].y); }
        if (a[k].z > 0.f) { u32 s = atomicAdd(&cnt, 1u); if (s < TCAP) buf[s] = ((u64)(((n0 + 2u) << 8) | b) << 32) | __float_as_uint(a[k].z); }
        if (a[k].w > 0.f) { u32 s = atomicAdd(&cnt, 1u); if (s < TCAP) buf[s] = ((u64)(((n0 + 3u) << 8) | b) << 32) | __float_as_uint(a[k].w); }
      }
    }
    if (csx > 0.f) umask[n0 + 0] = 1;
    if (csy > 0.f) umask[n0 + 1] = 1;
    if (csz > 0.f) umask[n0 + 2] = 1;
    if (csw > 0.f) umask[n0 + 3] = 1;
  }
  __syncthreads();
  u32 c = cnt > TCAP ? TCAP : cnt;
  if (threadIdx.x == 0) gbase = (u32)atomicAdd(&counters[2], (int)c);
  __syncthreads();
  for (u32 i = threadIdx.x; i < c; i += 256) trip[gbase + i] = buf[i];
}

// compact mask list from umask bytes + count num_neis
__global__ __launch_bounds__(256) void k_compact(const unsigned char* __restrict__ umask,
                                                 int* __restrict__ mlist,
                                                 int* __restrict__ counters) {
  int n = blockIdx.x * 256 + threadIdx.x;
  bool on = (n < NN);
  int lane = threadIdx.x & 63;
  bool pred = on && (umask[on ? n : 0] != 0);
  u64 bm = __ballot(pred);
  int cnt = __popcll(bm);
  if (cnt) {
    int leader = __ffsll((u64)bm) - 1;
    int base = 0;
    if (lane == leader) base = atomicAdd(&counters[0], cnt);
    base = __shfl(base, leader);
    if (pred) mlist[base + __popcll(bm & ((1ull << lane) - 1ull))] = n;
  }
}

// fused gather: fw2[n] = feat[n]@w2 for mask rows ONLY, and means += feat[n]
// (same feat rows read once). Wave per row, grid-stride.
__global__ __launch_bounds__(256) void k_fw2m(const float* __restrict__ feat,
                                              const float* __restrict__ w2,
                                              const int* __restrict__ mlist,
                                              const int* __restrict__ counters,
                                              float* __restrict__ fw2,
                                              float* __restrict__ means) {
  __shared__ float part[4][DD];
  int nm = counters[0];
  int wv = threadIdx.x >> 6;
  int lane = threadIdx.x & 63;
  int wave = blockIdx.x * 4 + wv;
  int stride = gridDim.x * 4;
  f4 w4 = ((const f4*)w2)[lane];
  f4 acc = {0.f, 0.f, 0.f, 0.f};
  for (int j = wave; j < nm; j += stride) {
    int n = mlist[j];
    f4 f = ((const f4*)(feat + (size_t)n * DD))[lane];
    acc.x += f.x; acc.y += f.y; acc.z += f.z; acc.w += f.w;
    float d = f.x * w4.x + f.y * w4.y + f.z * w4.z + f.w * w4.w;
#pragma unroll
    for (int off = 32; off; off >>= 1) d += __shfl_down(d, off);
    if (lane == 0) fw2[n] = d;
  }
  ((f4*)part[wv])[lane] = acc;
  __syncthreads();
  int d = threadIdx.x;
  float vv = part[0][d] + part[1][d] + part[2][d] + part[3][d];
  atomicAdd(&means[d], vv);
}

// s1 accumulation from sparse triplets: s1[n] += a * relu((hw1[b]+1)+fw2[n])
__global__ __launch_bounds__(256) void k_s1(const u64* __restrict__ trip,
                                            const int* __restrict__ counters,
                                            const float* __restrict__ hw1,
                                            const float* __restrict__ fw2,
                                            float* __restrict__ s1) {
  int tc = counters[2];
  for (int i = blockIdx.x * 256 + threadIdx.x; i < tc; i += gridDim.x * 256) {
    u64 t = trip[i];
    u32 key = (u32)(t >> 32);
    int n = (int)(key >> 8);
    int b = (int)(key & 255u);
    float a = __uint_as_float((u32)t);
    float h = hw1[b] + 1.0f;                 // same association as round 7
    float val = a * fmaxf(h + fw2[n], 0.0f);
    if (val > 0.0f) atomicAdd(&s1[n], val);
  }
}

// fused valid-compaction + finalize over mask rows: vidx/vlog, p1 in place, sum_p1
__global__ __launch_bounds__(256) void k_vfin(float* __restrict__ s1p1,
                                              const int* __restrict__ mlist,
                                              int* __restrict__ counters,
                                              int* __restrict__ vidx,
                                              float* __restrict__ vlog,
                                              float* __restrict__ scal) {
  int nm = counters[0];
  float nnf = (float)nm;
  int lane = threadIdx.x & 63;
  float local = 0.0f;
  for (int j0 = blockIdx.x * 256; j0 < nm; j0 += gridDim.x * 256) {
    int j = j0 + threadIdx.x;
    bool on = (j < nm);
    int n = on ? mlist[j] : 0;
    float s = on ? s1p1[n] : 0.0f;
    bool pred = on && (s > 0.0f);
    u64 bm = __ballot(pred);
    int cnt = __popcll(bm);
    if (cnt) {
      int leader = __ffsll((u64)bm) - 1;
      int base = 0;
      if (lane == leader) base = atomicAdd(&counters[1], cnt);
      base = __shfl(base, leader);
      if (pred) {
        int slot = base + __popcll(bm & ((1ull << lane) - 1ull));
        float p = s / nnf;
        s1p1[n] = p;
        vidx[slot] = n;
        vlog[slot] = logf(p);
        local += p;
      }
    }
  }
#pragma unroll
  for (int off = 32; off; off >>= 1) local += __shfl_down(local, off);
  if (lane == 0 && local != 0.0f) atomicAdd(&scal[0], local);
}

// 4 blocks per sample: partial argmax over valid list, u64 atomicMax merge
__global__ __launch_bounds__(256) void k_sample(const int* __restrict__ vidx,
                                                const float* __restrict__ vlog,
                                                const int* __restrict__ counters,
                                                u64* __restrict__ slots) {
  __shared__ u64 sk[256];
  int s = blockIdx.x >> 2;
  int quarter = blockIdx.x & 3;
  int nv = counters[1];
  u64 best = 0ull;
  u32 base = (u32)s * (u32)NN;
#pragma unroll 2
  for (int j = quarter * 256 + threadIdx.x; j < nv; j += 1024) {
    int n = vidx[j];
    uint2 r = tf2x32(0u, base + (u32)n);
    float g = gumbel_from_bits(r.x ^ r.y) + vlog[j];
    u64 key = pack_key(g, n);
    if (key > best) best = key;
  }
  sk[threadIdx.x] = best;
  __syncthreads();
#pragma unroll
  for (int off = 128; off; off >>= 1) {
    if (threadIdx.x < off) {
      u64 o = sk[threadIdx.x + off];
      if (o > sk[threadIdx.x]) sk[threadIdx.x] = o;
    }
    __syncthreads();
  }
  if (threadIdx.x == 0) atomicMax(&slots[s], sk[0]);
}

// loss_acc = sum over valid rows of p_u * ||f[row]-means||^2 (wave per row)
__global__ void k_loss(const float* __restrict__ feat, const float* __restrict__ means,
                       const float* __restrict__ s1p1, const int* __restrict__ vidx,
                       const int* __restrict__ counters, float* __restrict__ scal) {
  __shared__ float ms[DD];
  ms[threadIdx.x] = means[threadIdx.x];
  __syncthreads();
  int nv = counters[1];
  float spu = scal[0];
  int gw = blockIdx.x * 4 + (threadIdx.x >> 6);
  int tw = gridDim.x * 4;
  int lane = threadIdx.x & 63;
  float wacc = 0.0f;
  for (int j = gw; j < nv; j += tw) {
    int r = vidx[j];
    float4 f4v = ((const float4*)(feat + (size_t)r * DD))[lane];
    float4 m4 = ((const float4*)ms)[lane];
    float dx = f4v.x - m4.x, dy = f4v.y - m4.y, dz = f4v.z - m4.z, dw = f4v.w - m4.w;
    float val = dx * dx + dy * dy + dz * dz + dw * dw;
#pragma unroll
    for (int off = 32; off; off >>= 1) val += __shfl_down(val, off);
    if (lane == 0) wacc += (s1p1[r] / spu) * val;
  }
  if (lane == 0) atomicAdd(&scal[1], wacc);
}

// fused epilogue: blocks 0..255 copy x_u rows (2 samples each);
// blocks 256..511 write support row b (coalesced), gathering adj
__global__ __launch_bounds__(512) void k_tail(const float* __restrict__ feat,
                                              const float* __restrict__ adj,
                                              const float* __restrict__ s1p1,
                                              const u64* __restrict__ slots,
                                              const float* __restrict__ scal,
                                              float* __restrict__ out) {
  int blk = blockIdx.x;
  if (blk < 256) {
    int s = blk * 2 + (threadIdx.x >> 8);
    int t = threadIdx.x & 255;
    int idx = (int)(~(u32)slots[s]);
    out[(size_t)s * DD + t] = feat[(size_t)idx * DD + t];
  } else {
    int b = blk - 256;
    int s = threadIdx.x;  // 0..511
    int idx = (int)(~(u32)slots[s]);
    float denom = s1p1[idx] * (float)SS;
    out[(size_t)SS * DD + (size_t)b * SS + s] = adj[(size_t)b * NN + idx] / denom;
    if (b == 255 && s == 0) out[(size_t)SS * DD + (size_t)BB * SS] = scal[1] / (float)DD;
  }
}

extern "C" void kernel_launch(void* const* d_in, const int* in_sizes, int n_in,
                              void* d_out, int out_size, void* d_ws, size_t ws_size,
                              hipStream_t stream) {
  const float* feat = (const float*)d_in[0];
  const float* adj  = (const float*)d_in[1];
  const float* w1   = (const float*)d_in[2];
  const float* w2   = (const float*)d_in[3];
  const int*   v    = (const int*)d_in[4];
  float* out = (float*)d_out;

  float* ws    = (float*)d_ws;
  float* fw2   = ws;                          // [NN] (only mask entries written/read)
  float* s1p1  = ws + (size_t)NN;             // [NN] s1 then p1 in place
  float* vlog  = ws + 2 * (size_t)NN;         // [NN]
  int*   vidx  = (int*)(ws + 3 * (size_t)NN); // [NN]
  int*   mlist = (int*)(ws + 4 * (size_t)NN); // [NN]
  unsigned char* umask = (unsigned char*)(ws + 5 * (size_t)NN); // [NN] bytes
  u64*   trip  = (u64*)(ws + 5 * (size_t)NN + NQ); // [TMAX] packed {n<<8|b, bits(a)}
  float* tail  = ws + 5 * (size_t)NN + NQ + 2 * (size_t)TMAX;
  float* hw1   = tail;                        // [256]
  float* means = tail + 256;                  // [256]
  float* scal  = tail + 512;                  // [16]: [0]=sum_p1 [1]=loss; ints at +2
  int*   counters = (int*)(scal + 2);         // [0]=n_mask [1]=n_valid [2]=tcnt
  u64*   slots = (u64*)(tail + 544);          // [512]

  k_pre<<<528, 256, 0, stream>>>(feat, w1, v, hw1, s1p1, (u32*)umask, means, scal, slots);
  k_adj_pass<<<QB * NCH, 256, 0, stream>>>(adj, umask, trip, counters);
  k_compact<<<(NN + 255) / 256, 256, 0, stream>>>(umask, mlist, counters);
  k_fw2m<<<512, 256, 0, stream>>>(feat, w2, mlist, counters, fw2, means);
  k_s1<<<64, 256, 0, stream>>>(trip, counters, hw1, fw2, s1p1);
  k_vfin<<<128, 256, 0, stream>>>(s1p1, mlist, counters, vidx, vlog, scal);
  k_sample<<<SS * 4, 256, 0, stream>>>(vidx, vlog, counters, slots);
  k_loss<<<256, 256, 0, stream>>>(feat, means, s1p1, vidx, counters, scal);
  k_tail<<<512, 512, 0, stream>>>(feat, adj, s1p1, slots, scal, out);
}

// Round 9
// 193.141 us; speedup vs baseline: 1.7835x; 1.0385x over previous
//
#include <hip/hip_runtime.h>
#include <math.h>
#include <stdint.h>

#define NN 200000   // nodes
#define NQ 50000    // NN/4 column quads
#define DD 256      // feature dim
#define BB 256      // batch rows of adj
#define SS 512      // output samples
#define QB 196      // ceil(NQ/256) column blocks
#define NCH 16      // b-chunks (16 b each)
#define TCAP 1024   // per-block LDS triplet cap (mean 8.2/block)
#define TMAX (1u<<20) // global triplet buffer entries (mean 25.6K)
#define CB 782      // ceil(NN/256) compact blocks

// PRNG: threefry_partitionable: elem i -> tf(0, i), bits = out0 ^ out1
// (verified bit-exact PASS, absmax 0.0, rounds 2-8)
// Round-5 lesson: no RMW atomics in bulk passes; byte-store umask + sparse
// atomicAdd + one LDS-staged global-atomic append per block are fine.

typedef unsigned int u32;
typedef unsigned long long u64;
typedef float f4 __attribute__((ext_vector_type(4)));

// ---------------- threefry2x32, key = (0,1)  (jax.random.key(1)) ----------------
__device__ __forceinline__ uint2 tf2x32(u32 x0, u32 x1) {
  const u32 ks0 = 0u, ks1 = 1u, ks2 = 0x1BD11BDBu;
  x0 += ks0; x1 += ks1;
#define TFR(r) { x0 += x1; x1 = (x1 << (r)) | (x1 >> (32 - (r))); x1 ^= x0; }
  TFR(13) TFR(15) TFR(26) TFR(6)
  x0 += ks1; x1 += ks2 + 1u;
  TFR(17) TFR(29) TFR(16) TFR(24)
  x0 += ks2; x1 += ks0 + 2u;
  TFR(13) TFR(15) TFR(26) TFR(6)
  x0 += ks0; x1 += ks1 + 3u;
  TFR(17) TFR(29) TFR(16) TFR(24)
  x0 += ks1; x1 += ks2 + 4u;
  TFR(13) TFR(15) TFR(26) TFR(6)
  x0 += ks2; x1 += ks0 + 5u;
#undef TFR
  return make_uint2(x0, x1);
}

__device__ __forceinline__ float gumbel_from_bits(u32 bits) {
  const float TINY = 1.17549435e-38f;
  float f = __uint_as_float((bits >> 9) | 0x3f800000u) - 1.0f; // [0,1)
  float x = f + TINY;
  x = fmaxf(TINY, x);
  return -logf(-logf(x));
}

// pack (gumbel g, index n) so u64-max == (argmax g, first-index tie-break)
__device__ __forceinline__ u64 pack_key(float g, int n) {
  u32 u = __float_as_uint(g);
  u32 m = (u & 0x80000000u) ? ~u : (u | 0x80000000u);
  return ((u64)m << 32) | (u32)(~(u32)n);
}

// ---------------- kernels ----------------
// k_pre: zero umask words + means/scal/slots (s1 zeroing moved to k_compact)
__global__ __launch_bounds__(256) void k_pre(u32* __restrict__ umaskw,
                                             float* __restrict__ means,
                                             float* __restrict__ scal,
                                             u64* __restrict__ slots) {
  int i = blockIdx.x * 256 + threadIdx.x;
  int stride = gridDim.x * 256;
  for (int j = i; j < NQ; j += stride) umaskw[j] = 0u;
  if (i < 256) means[i] = 0.0f;
  if (i < 16) scal[i] = 0.0f;
  if (i < SS) slots[i] = 0ull;
}

// single BW-bound pass over adj: col_sum partials -> umask bytes; sparse
// triplets {n,b,a} appended via LDS staging + one global atomic per block.
__global__ __launch_bounds__(256) void k_adj_pass(const float* __restrict__ adj,
                                                  unsigned char* __restrict__ umask,
                                                  u64* __restrict__ trip,
                                                  int* __restrict__ counters) {
  __shared__ u32 cnt, gbase;
  __shared__ u64 buf[TCAP];
  if (threadIdx.x == 0) cnt = 0u;
  __syncthreads();
  int cb = blockIdx.x % QB;   // column block (1024 cols)
  int ch = blockIdx.x / QB;   // b-chunk 0..15 (16 b each)
  int b0 = ch * 16;
  int q = cb * 256 + threadIdx.x;
  if (q < NQ) {
    const float4* adj4 = (const float4*)adj;
    float csx = 0.f, csy = 0.f, csz = 0.f, csw = 0.f;
    u32 n0 = (u32)q * 4u;
    for (int bb = 0; bb < 16; bb += 4) {
      float4 a[4];
#pragma unroll
      for (int k = 0; k < 4; ++k) a[k] = adj4[(size_t)(b0 + bb + k) * NQ + q];
#pragma unroll
      for (int k = 0; k < 4; ++k) {
        u32 b = (u32)(b0 + bb + k);
        csx += a[k].x; csy += a[k].y; csz += a[k].z; csw += a[k].w;
        if (a[k].x > 0.f) { u32 s = atomicAdd(&cnt, 1u); if (s < TCAP) buf[s] = ((u64)(((n0 + 0u) << 8) | b) << 32) | __float_as_uint(a[k].x); }
        if (a[k].y > 0.f) { u32 s = atomicAdd(&cnt, 1u); if (s < TCAP) buf[s] = ((u64)(((n0 + 1u) << 8) | b) << 32) | __float_as_uint(a[k].y); }
        if (a[k].z > 0.f) { u32 s = atomicAdd(&cnt, 1u); if (s < TCAP) buf[s] = ((u64)(((n0 + 2u) << 8) | b) << 32) | __float_as_uint(a[k].z); }
        if (a[k].w > 0.f) { u32 s = atomicAdd(&cnt, 1u); if (s < TCAP) buf[s] = ((u64)(((n0 + 3u) << 8) | b) << 32) | __float_as_uint(a[k].w); }
      }
    }
    if (csx > 0.f) umask[n0 + 0] = 1;
    if (csy > 0.f) umask[n0 + 1] = 1;
    if (csz > 0.f) umask[n0 + 2] = 1;
    if (csw > 0.f) umask[n0 + 3] = 1;
  }
  __syncthreads();
  u32 c = cnt > TCAP ? TCAP : cnt;
  if (threadIdx.x == 0) gbase = (u32)atomicAdd(&counters[2], (int)c);
  __syncthreads();
  for (u32 i = threadIdx.x; i < c; i += 256) trip[gbase + i] = buf[i];
}

// heterogeneous: blocks <CB compact mask list + zero s1 for mask rows;
// blocks CB..CB+15 compute hw1 = feat[v]@w1 (consumed two launches later)
__global__ __launch_bounds__(256) void k_compact(const unsigned char* __restrict__ umask,
                                                 int* __restrict__ mlist,
                                                 int* __restrict__ counters,
                                                 float* __restrict__ s1,
                                                 const float* __restrict__ feat,
                                                 const float* __restrict__ w1,
                                                 const int* __restrict__ v,
                                                 float* __restrict__ hw1) {
  int blk = blockIdx.x;
  if (blk < CB) {
    int n = blk * 256 + threadIdx.x;
    bool on = (n < NN);
    int lane = threadIdx.x & 63;
    bool pred = on && (umask[on ? n : 0] != 0);
    u64 bm = __ballot(pred);
    int cnt = __popcll(bm);
    if (cnt) {
      int leader = __ffsll((u64)bm) - 1;
      int base = 0;
      if (lane == leader) base = atomicAdd(&counters[0], cnt);
      base = __shfl(base, leader);
      if (pred) {
        mlist[base + __popcll(bm & ((1ull << lane) - 1ull))] = n;
        s1[n] = 0.0f;   // only mask rows are ever accumulated/read downstream
      }
    }
  } else {
    int wv = threadIdx.x >> 6;
    int lane = threadIdx.x & 63;
    int r0 = ((blk - CB) * 4 + wv) * 4;  // rows 0..255
    f4 w4 = ((const f4*)w1)[lane];
    f4 f[4];
#pragma unroll
    for (int k = 0; k < 4; ++k)
      f[k] = ((const f4*)(feat + (size_t)v[r0 + k] * DD))[lane];
    float d[4];
#pragma unroll
    for (int k = 0; k < 4; ++k)
      d[k] = f[k].x * w4.x + f[k].y * w4.y + f[k].z * w4.z + f[k].w * w4.w;
#pragma unroll
    for (int off = 32; off; off >>= 1) {
#pragma unroll
      for (int k = 0; k < 4; ++k) d[k] += __shfl_down(d[k], off);
    }
    if (lane == 0) {
#pragma unroll
      for (int k = 0; k < 4; ++k) hw1[r0 + k] = d[k];
    }
  }
}

// fused gather: fw2[n] = feat[n]@w2 for mask rows ONLY, and means += feat[n]
__global__ __launch_bounds__(256) void k_fw2m(const float* __restrict__ feat,
                                              const float* __restrict__ w2,
                                              const int* __restrict__ mlist,
                                              const int* __restrict__ counters,
                                              float* __restrict__ fw2,
                                              float* __restrict__ means) {
  __shared__ float part[4][DD];
  int nm = counters[0];
  int wv = threadIdx.x >> 6;
  int lane = threadIdx.x & 63;
  int wave = blockIdx.x * 4 + wv;
  int stride = gridDim.x * 4;
  f4 w4 = ((const f4*)w2)[lane];
  f4 acc = {0.f, 0.f, 0.f, 0.f};
  for (int j = wave; j < nm; j += stride) {
    int n = mlist[j];
    f4 f = ((const f4*)(feat + (size_t)n * DD))[lane];
    acc.x += f.x; acc.y += f.y; acc.z += f.z; acc.w += f.w;
    float d = f.x * w4.x + f.y * w4.y + f.z * w4.z + f.w * w4.w;
#pragma unroll
    for (int off = 32; off; off >>= 1) d += __shfl_down(d, off);
    if (lane == 0) fw2[n] = d;
  }
  ((f4*)part[wv])[lane] = acc;
  __syncthreads();
  int d = threadIdx.x;
  float vv = part[0][d] + part[1][d] + part[2][d] + part[3][d];
  atomicAdd(&means[d], vv);
}

// s1 accumulation from sparse triplets: s1[n] += a * relu((hw1[b]+1)+fw2[n])
__global__ __launch_bounds__(256) void k_s1(const u64* __restrict__ trip,
                                            const int* __restrict__ counters,
                                            const float* __restrict__ hw1,
                                            const float* __restrict__ fw2,
                                            float* __restrict__ s1) {
  int tc = counters[2];
  for (int i = blockIdx.x * 256 + threadIdx.x; i < tc; i += gridDim.x * 256) {
    u64 t = trip[i];
    u32 key = (u32)(t >> 32);
    int n = (int)(key >> 8);
    int b = (int)(key & 255u);
    float a = __uint_as_float((u32)t);
    float h = hw1[b] + 1.0f;
    float val = a * fmaxf(h + fw2[n], 0.0f);
    if (val > 0.0f) atomicAdd(&s1[n], val);
  }
}

// fused valid-compaction + finalize over mask rows: vidx/vlog, p1 in place, sum_p1
__global__ __launch_bounds__(256) void k_vfin(float* __restrict__ s1p1,
                                              const int* __restrict__ mlist,
                                              int* __restrict__ counters,
                                              int* __restrict__ vidx,
                                              float* __restrict__ vlog,
                                              float* __restrict__ scal) {
  int nm = counters[0];
  float nnf = (float)nm;
  int lane = threadIdx.x & 63;
  float local = 0.0f;
  for (int j0 = blockIdx.x * 256; j0 < nm; j0 += gridDim.x * 256) {
    int j = j0 + threadIdx.x;
    bool on = (j < nm);
    int n = on ? mlist[j] : 0;
    float s = on ? s1p1[n] : 0.0f;
    bool pred = on && (s > 0.0f);
    u64 bm = __ballot(pred);
    int cnt = __popcll(bm);
    if (cnt) {
      int leader = __ffsll((u64)bm) - 1;
      int base = 0;
      if (lane == leader) base = atomicAdd(&counters[1], cnt);
      base = __shfl(base, leader);
      if (pred) {
        int slot = base + __popcll(bm & ((1ull << lane) - 1ull));
        float p = s / nnf;
        s1p1[n] = p;
        vidx[slot] = n;
        vlog[slot] = logf(p);
        local += p;
      }
    }
  }
#pragma unroll
  for (int off = 32; off; off >>= 1) local += __shfl_down(local, off);
  if (lane == 0 && local != 0.0f) atomicAdd(&scal[0], local);
}

// heterogeneous: blocks 0..2047 sample argmax (VALU-bound, 4 blocks/sample);
// blocks 2048..2303 loss gather (memory-bound) — loss hides under sample.
__global__ __launch_bounds__(256) void k_mix(const int* __restrict__ vidx,
                                             const float* __restrict__ vlog,
                                             const int* __restrict__ counters,
                                             u64* __restrict__ slots,
                                             const float* __restrict__ feat,
                                             const float* __restrict__ means,
                                             const float* __restrict__ s1p1,
                                             float* __restrict__ scal) {
  __shared__ u64 sk[256];
  __shared__ float ms[DD];
  int blk = blockIdx.x;
  int nv = counters[1];
  if (blk < SS * 4) {
    int s = blk >> 2;
    int quarter = blk & 3;
    u64 best = 0ull;
    u32 base = (u32)s * (u32)NN;
#pragma unroll 2
    for (int j = quarter * 256 + threadIdx.x; j < nv; j += 1024) {
      int n = vidx[j];
      uint2 r = tf2x32(0u, base + (u32)n);
      float g = gumbel_from_bits(r.x ^ r.y) + vlog[j];
      u64 key = pack_key(g, n);
      if (key > best) best = key;
    }
    sk[threadIdx.x] = best;
    __syncthreads();
#pragma unroll
    for (int off = 128; off; off >>= 1) {
      if (threadIdx.x < off) {
        u64 o = sk[threadIdx.x + off];
        if (o > sk[threadIdx.x]) sk[threadIdx.x] = o;
      }
      __syncthreads();
    }
    if (threadIdx.x == 0) atomicMax(&slots[s], sk[0]);
  } else {
    ms[threadIdx.x] = means[threadIdx.x];
    __syncthreads();
    float spu = scal[0];
    int gw = (blk - SS * 4) * 4 + (threadIdx.x >> 6);
    int tw = 256 * 4;
    int lane = threadIdx.x & 63;
    float wacc = 0.0f;
    for (int j = gw; j < nv; j += tw) {
      int r = vidx[j];
      float4 f4v = ((const float4*)(feat + (size_t)r * DD))[lane];
      float4 m4 = ((const float4*)ms)[lane];
      float dx = f4v.x - m4.x, dy = f4v.y - m4.y, dz = f4v.z - m4.z, dw = f4v.w - m4.w;
      float val = dx * dx + dy * dy + dz * dz + dw * dw;
#pragma unroll
      for (int off = 32; off; off >>= 1) val += __shfl_down(val, off);
      if (lane == 0) wacc += (s1p1[r] / spu) * val;
    }
    if (lane == 0) atomicAdd(&scal[1], wacc);
  }
}

// fused epilogue: blocks 0..255 copy x_u rows (2 samples each);
// blocks 256..511 write support row b (coalesced), gathering adj
__global__ __launch_bounds__(512) void k_tail(const float* __restrict__ feat,
                                              const float* __restrict__ adj,
                                              const float* __restrict__ s1p1,
                                              const u64* __restrict__ slots,
                                              const float* __restrict__ scal,
                                              float* __restrict__ out) {
  int blk = blockIdx.x;
  if (blk < 256) {
    int s = blk * 2 + (threadIdx.x >> 8);
    int t = threadIdx.x & 255;
    int idx = (int)(~(u32)slots[s]);
    out[(size_t)s * DD + t] = feat[(size_t)idx * DD + t];
  } else {
    int b = blk - 256;
    int s = threadIdx.x;  // 0..511
    int idx = (int)(~(u32)slots[s]);
    float denom = s1p1[idx] * (float)SS;
    out[(size_t)SS * DD + (size_t)b * SS + s] = adj[(size_t)b * NN + idx] / denom;
    if (b == 255 && s == 0) out[(size_t)SS * DD + (size_t)BB * SS] = scal[1] / (float)DD;
  }
}

extern "C" void kernel_launch(void* const* d_in, const int* in_sizes, int n_in,
                              void* d_out, int out_size, void* d_ws, size_t ws_size,
                              hipStream_t stream) {
  const float* feat = (const float*)d_in[0];
  const float* adj  = (const float*)d_in[1];
  const float* w1   = (const float*)d_in[2];
  const float* w2   = (const float*)d_in[3];
  const int*   v    = (const int*)d_in[4];
  float* out = (float*)d_out;

  float* ws    = (float*)d_ws;
  float* fw2   = ws;                          // [NN] (only mask entries written/read)
  float* s1p1  = ws + (size_t)NN;             // [NN] s1 then p1 in place (mask rows only)
  float* vlog  = ws + 2 * (size_t)NN;         // [NN]
  int*   vidx  = (int*)(ws + 3 * (size_t)NN); // [NN]
  int*   mlist = (int*)(ws + 4 * (size_t)NN); // [NN]
  unsigned char* umask = (unsigned char*)(ws + 5 * (size_t)NN); // [NN] bytes
  u64*   trip  = (u64*)(ws + 5 * (size_t)NN + NQ); // [TMAX] packed {n<<8|b, bits(a)}
  float* tail  = ws + 5 * (size_t)NN + NQ + 2 * (size_t)TMAX;
  float* hw1   = tail;                        // [256]
  float* means = tail + 256;                  // [256]
  float* scal  = tail + 512;                  // [16]: [0]=sum_p1 [1]=loss; ints at +2
  int*   counters = (int*)(scal + 2);         // [0]=n_mask [1]=n_valid [2]=tcnt
  u64*   slots = (u64*)(tail + 544);          // [512]

  k_pre<<<128, 256, 0, stream>>>((u32*)umask, means, scal, slots);
  k_adj_pass<<<QB * NCH, 256, 0, stream>>>(adj, umask, trip, counters);
  k_compact<<<CB + 16, 256, 0, stream>>>(umask, mlist, counters, s1p1, feat, w1, v, hw1);
  k_fw2m<<<512, 256, 0, stream>>>(feat, w2, mlist, counters, fw2, means);
  k_s1<<<64, 256, 0, stream>>>(trip, counters, hw1, fw2, s1p1);
  k_vfin<<<128, 256, 0, stream>>>(s1p1, mlist, counters, vidx, vlog, scal);
  k_mix<<<SS * 4 + 256, 256, 0, stream>>>(vidx, vlog, counters, slots, feat, means, s1p1, scal);
  k_tail<<<512, 512, 0, stream>>>(feat, adj, s1p1, slots, scal, out);
}

// Round 10
// 184.395 us; speedup vs baseline: 1.8681x; 1.0474x over previous
//
#include <hip/hip_runtime.h>
#include <math.h>
#include <stdint.h>

#define NN 200000   // nodes
#define NQ 50000    // NN/4 column quads
#define DD 256      // feature dim
#define BB 256      // batch rows of adj
#define SS 512      // output samples
#define QB 196      // ceil(NQ/256) column blocks
#define NCH 16      // b-chunks (16 b each)
#define NBLK (QB * NCH) // 3136 adj-pass blocks
#define RCAP 64     // per-block triplet region (mean 8.2, P(>64)~1e-35)

// PRNG: threefry_partitionable: elem i -> tf(0, i), bits = out0 ^ out1
// (verified bit-exact PASS, absmax 0.0, rounds 2-9)
// Round-5 lesson: no RMW atomics on shared hot lines in bulk passes.
// Round-10 design: per-chunk mask slices + fixed triplet regions -> the adj
// pass needs NO pre-zeroed state and NO global atomics; k_pre eliminated.

typedef unsigned int u32;
typedef unsigned long long u64;
typedef float f4 __attribute__((ext_vector_type(4)));

// ---------------- threefry2x32, key = (0,1)  (jax.random.key(1)) ----------------
__device__ __forceinline__ uint2 tf2x32(u32 x0, u32 x1) {
  const u32 ks0 = 0u, ks1 = 1u, ks2 = 0x1BD11BDBu;
  x0 += ks0; x1 += ks1;
#define TFR(r) { x0 += x1; x1 = (x1 << (r)) | (x1 >> (32 - (r))); x1 ^= x0; }
  TFR(13) TFR(15) TFR(26) TFR(6)
  x0 += ks1; x1 += ks2 + 1u;
  TFR(17) TFR(29) TFR(16) TFR(24)
  x0 += ks2; x1 += ks0 + 2u;
  TFR(13) TFR(15) TFR(26) TFR(6)
  x0 += ks0; x1 += ks1 + 3u;
  TFR(17) TFR(29) TFR(16) TFR(24)
  x0 += ks1; x1 += ks2 + 4u;
  TFR(13) TFR(15) TFR(26) TFR(6)
  x0 += ks2; x1 += ks0 + 5u;
#undef TFR
  return make_uint2(x0, x1);
}

__device__ __forceinline__ float gumbel_from_bits(u32 bits) {
  const float TINY = 1.17549435e-38f;
  float f = __uint_as_float((bits >> 9) | 0x3f800000u) - 1.0f; // [0,1)
  float x = f + TINY;
  x = fmaxf(TINY, x);
  return -logf(-logf(x));
}

// pack (gumbel g, index n) so u64-max == (argmax g, first-index tie-break)
__device__ __forceinline__ u64 pack_key(float g, int n) {
  u32 u = __float_as_uint(g);
  u32 m = (u & 0x80000000u) ? ~u : (u | 0x80000000u);
  return ((u64)m << 32) | (u32)(~(u32)n);
}

// ---------------- kernels ----------------
// FIRST kernel. BW-bound pass over adj: per-chunk packed mask words written
// unconditionally (no pre-zero needed); triplets to fixed per-block regions
// (no global atomics). Block 0 zeros the small downstream scalars.
__global__ __launch_bounds__(256) void k_adj_pass(const float* __restrict__ adj,
                                                  u32* __restrict__ umaskw,   // [NCH*NQ]
                                                  u64* __restrict__ trip,     // [NBLK*RCAP]
                                                  u32* __restrict__ tripcnt,  // [NBLK]
                                                  float* __restrict__ means,
                                                  float* __restrict__ scal,
                                                  u64* __restrict__ slots) {
  __shared__ u32 cnt;
  if (threadIdx.x == 0) cnt = 0u;
  if (blockIdx.x == 0) {
    int t = threadIdx.x;
    for (int j = t; j < SS; j += 256) slots[j] = 0ull;
    means[t] = 0.0f;
    if (t < 16) scal[t] = 0.0f;   // includes counters aliased at scal[2..]
  }
  __syncthreads();
  int cb = blockIdx.x % QB;   // column block (1024 cols)
  int ch = blockIdx.x / QB;   // b-chunk 0..15 (16 b each)
  int b0 = ch * 16;
  int q = cb * 256 + threadIdx.x;
  u64* reg = trip + (size_t)blockIdx.x * RCAP;
  if (q < NQ) {
    const float4* adj4 = (const float4*)adj;
    float csx = 0.f, csy = 0.f, csz = 0.f, csw = 0.f;
    u32 n0 = (u32)q * 4u;
    for (int bb = 0; bb < 16; bb += 4) {
      float4 a[4];
#pragma unroll
      for (int k = 0; k < 4; ++k) a[k] = adj4[(size_t)(b0 + bb + k) * NQ + q];
#pragma unroll
      for (int k = 0; k < 4; ++k) {
        u32 b = (u32)(b0 + bb + k);
        csx += a[k].x; csy += a[k].y; csz += a[k].z; csw += a[k].w;
        if (a[k].x > 0.f) { u32 s = atomicAdd(&cnt, 1u); if (s < RCAP) reg[s] = ((u64)(((n0 + 0u) << 8) | b) << 32) | __float_as_uint(a[k].x); }
        if (a[k].y > 0.f) { u32 s = atomicAdd(&cnt, 1u); if (s < RCAP) reg[s] = ((u64)(((n0 + 1u) << 8) | b) << 32) | __float_as_uint(a[k].y); }
        if (a[k].z > 0.f) { u32 s = atomicAdd(&cnt, 1u); if (s < RCAP) reg[s] = ((u64)(((n0 + 2u) << 8) | b) << 32) | __float_as_uint(a[k].z); }
        if (a[k].w > 0.f) { u32 s = atomicAdd(&cnt, 1u); if (s < RCAP) reg[s] = ((u64)(((n0 + 3u) << 8) | b) << 32) | __float_as_uint(a[k].w); }
      }
    }
    u32 m = (csx > 0.f ? 1u : 0u) | (csy > 0.f ? 0x100u : 0u) |
            (csz > 0.f ? 0x10000u : 0u) | (csw > 0.f ? 0x1000000u : 0u);
    umaskw[(size_t)ch * NQ + q] = m;   // unconditional: slice fully covered
  }
  __syncthreads();
  if (threadIdx.x == 0) tripcnt[blockIdx.x] = cnt > RCAP ? RCAP : cnt;
}

// heterogeneous: blocks <QB compact mask list (thread per quad, OR 16 slices)
// + zero s1 for mask rows; blocks QB..QB+15 compute hw1 = feat[v]@w1
__global__ __launch_bounds__(256) void k_compact(const u32* __restrict__ umaskw,
                                                 int* __restrict__ mlist,
                                                 int* __restrict__ counters,
                                                 float* __restrict__ s1,
                                                 const float* __restrict__ feat,
                                                 const float* __restrict__ w1,
                                                 const int* __restrict__ v,
                                                 float* __restrict__ hw1) {
  int blk = blockIdx.x;
  if (blk < QB) {
    int q = blk * 256 + threadIdx.x;
    u32 m = 0u;
    if (q < NQ) {
#pragma unroll
      for (int ch = 0; ch < NCH; ++ch) m |= umaskw[(size_t)ch * NQ + q];
    }
    int lane = threadIdx.x & 63;
#pragma unroll
    for (int k = 0; k < 4; ++k) {
      bool pred = ((m >> (8 * k)) & 1u) != 0u;
      u64 bm = __ballot(pred);
      int c = __popcll(bm);
      if (c) {
        int leader = __ffsll((u64)bm) - 1;
        int base = 0;
        if (lane == leader) base = atomicAdd(&counters[0], c);
        base = __shfl(base, leader);
        if (pred) {
          int n = q * 4 + k;
          mlist[base + __popcll(bm & ((1ull << lane) - 1ull))] = n;
          s1[n] = 0.0f;   // only mask rows are accumulated/read downstream
        }
      }
    }
  } else {
    int wv = threadIdx.x >> 6;
    int lane = threadIdx.x & 63;
    int r0 = ((blk - QB) * 4 + wv) * 4;  // rows 0..255
    f4 w4 = ((const f4*)w1)[lane];
    f4 f[4];
#pragma unroll
    for (int k = 0; k < 4; ++k)
      f[k] = ((const f4*)(feat + (size_t)v[r0 + k] * DD))[lane];
    float d[4];
#pragma unroll
    for (int k = 0; k < 4; ++k)
      d[k] = f[k].x * w4.x + f[k].y * w4.y + f[k].z * w4.z + f[k].w * w4.w;
#pragma unroll
    for (int off = 32; off; off >>= 1) {
#pragma unroll
      for (int k = 0; k < 4; ++k) d[k] += __shfl_down(d[k], off);
    }
    if (lane == 0) {
#pragma unroll
      for (int k = 0; k < 4; ++k) hw1[r0 + k] = d[k];
    }
  }
}

// fused gather: fw2[n] = feat[n]@w2 for mask rows ONLY, and means += feat[n]
__global__ __launch_bounds__(256) void k_fw2m(const float* __restrict__ feat,
                                              const float* __restrict__ w2,
                                              const int* __restrict__ mlist,
                                              const int* __restrict__ counters,
                                              float* __restrict__ fw2,
                                              float* __restrict__ means) {
  __shared__ float part[4][DD];
  int nm = counters[0];
  int wv = threadIdx.x >> 6;
  int lane = threadIdx.x & 63;
  int wave = blockIdx.x * 4 + wv;
  int stride = gridDim.x * 4;
  f4 w4 = ((const f4*)w2)[lane];
  f4 acc = {0.f, 0.f, 0.f, 0.f};
  for (int j = wave; j < nm; j += stride) {
    int n = mlist[j];
    f4 f = ((const f4*)(feat + (size_t)n * DD))[lane];
    acc.x += f.x; acc.y += f.y; acc.z += f.z; acc.w += f.w;
    float d = f.x * w4.x + f.y * w4.y + f.z * w4.z + f.w * w4.w;
#pragma unroll
    for (int off = 32; off; off >>= 1) d += __shfl_down(d, off);
    if (lane == 0) fw2[n] = d;
  }
  ((f4*)part[wv])[lane] = acc;
  __syncthreads();
  int d = threadIdx.x;
  float vv = part[0][d] + part[1][d] + part[2][d] + part[3][d];
  atomicAdd(&means[d], vv);
}

// s1 accumulation from fixed triplet regions: thread per region
__global__ __launch_bounds__(256) void k_s1(const u64* __restrict__ trip,
                                            const u32* __restrict__ tripcnt,
                                            const float* __restrict__ hw1,
                                            const float* __restrict__ fw2,
                                            float* __restrict__ s1) {
  int r = blockIdx.x * 256 + threadIdx.x;
  if (r >= NBLK) return;
  u32 c = tripcnt[r];
  if (c > RCAP) c = RCAP;
  const u64* reg = trip + (size_t)r * RCAP;
  for (u32 i = 0; i < c; ++i) {
    u64 t = reg[i];
    u32 key = (u32)(t >> 32);
    int n = (int)(key >> 8);
    int b = (int)(key & 255u);
    float a = __uint_as_float((u32)t);
    float h = hw1[b] + 1.0f;
    float val = a * fmaxf(h + fw2[n], 0.0f);
    if (val > 0.0f) atomicAdd(&s1[n], val);
  }
}

// fused valid-compaction + finalize over mask rows: vidx/vlog, p1 in place, sum_p1
__global__ __launch_bounds__(256) void k_vfin(float* __restrict__ s1p1,
                                              const int* __restrict__ mlist,
                                              int* __restrict__ counters,
                                              int* __restrict__ vidx,
                                              float* __restrict__ vlog,
                                              float* __restrict__ scal) {
  int nm = counters[0];
  float nnf = (float)nm;
  int lane = threadIdx.x & 63;
  float local = 0.0f;
  for (int j0 = blockIdx.x * 256; j0 < nm; j0 += gridDim.x * 256) {
    int j = j0 + threadIdx.x;
    bool on = (j < nm);
    int n = on ? mlist[j] : 0;
    float s = on ? s1p1[n] : 0.0f;
    bool pred = on && (s > 0.0f);
    u64 bm = __ballot(pred);
    int cnt = __popcll(bm);
    if (cnt) {
      int leader = __ffsll((u64)bm) - 1;
      int base = 0;
      if (lane == leader) base = atomicAdd(&counters[1], cnt);
      base = __shfl(base, leader);
      if (pred) {
        int slot = base + __popcll(bm & ((1ull << lane) - 1ull));
        float p = s / nnf;
        s1p1[n] = p;
        vidx[slot] = n;
        vlog[slot] = logf(p);
        local += p;
      }
    }
  }
#pragma unroll
  for (int off = 32; off; off >>= 1) local += __shfl_down(local, off);
  if (lane == 0 && local != 0.0f) atomicAdd(&scal[0], local);
}

// heterogeneous: blocks 0..2047 sample argmax (VALU-bound, 4 blocks/sample);
// blocks 2048..2303 loss gather (memory-bound) — loss hides under sample.
__global__ __launch_bounds__(256) void k_mix(const int* __restrict__ vidx,
                                             const float* __restrict__ vlog,
                                             const int* __restrict__ counters,
                                             u64* __restrict__ slots,
                                             const float* __restrict__ feat,
                                             const float* __restrict__ means,
                                             const float* __restrict__ s1p1,
                                             float* __restrict__ scal) {
  __shared__ u64 sk[256];
  __shared__ float ms[DD];
  int blk = blockIdx.x;
  int nv = counters[1];
  if (blk < SS * 4) {
    int s = blk >> 2;
    int quarter = blk & 3;
    u64 best = 0ull;
    u32 base = (u32)s * (u32)NN;
#pragma unroll 2
    for (int j = quarter * 256 + threadIdx.x; j < nv; j += 1024) {
      int n = vidx[j];
      uint2 r = tf2x32(0u, base + (u32)n);
      float g = gumbel_from_bits(r.x ^ r.y) + vlog[j];
      u64 key = pack_key(g, n);
      if (key > best) best = key;
    }
    sk[threadIdx.x] = best;
    __syncthreads();
#pragma unroll
    for (int off = 128; off; off >>= 1) {
      if (threadIdx.x < off) {
        u64 o = sk[threadIdx.x + off];
        if (o > sk[threadIdx.x]) sk[threadIdx.x] = o;
      }
      __syncthreads();
    }
    if (threadIdx.x == 0) atomicMax(&slots[s], sk[0]);
  } else {
    ms[threadIdx.x] = means[threadIdx.x];
    __syncthreads();
    float spu = scal[0];
    int gw = (blk - SS * 4) * 4 + (threadIdx.x >> 6);
    int tw = 256 * 4;
    int lane = threadIdx.x & 63;
    float wacc = 0.0f;
    for (int j = gw; j < nv; j += tw) {
      int r = vidx[j];
      float4 f4v = ((const float4*)(feat + (size_t)r * DD))[lane];
      float4 m4 = ((const float4*)ms)[lane];
      float dx = f4v.x - m4.x, dy = f4v.y - m4.y, dz = f4v.z - m4.z, dw = f4v.w - m4.w;
      float val = dx * dx + dy * dy + dz * dz + dw * dw;
#pragma unroll
      for (int off = 32; off; off >>= 1) val += __shfl_down(val, off);
      if (lane == 0) wacc += (s1p1[r] / spu) * val;
    }
    if (lane == 0) atomicAdd(&scal[1], wacc);
  }
}

// fused epilogue: blocks 0..255 copy x_u rows (2 samples each);
// blocks 256..511 write support row b (coalesced), gathering adj
__global__ __launch_bounds__(512) void k_tail(const float* __restrict__ feat,
                                              const float* __restrict__ adj,
                                              const float* __restrict__ s1p1,
                                              const u64* __restrict__ slots,
                                              const float* __restrict__ scal,
                                              float* __restrict__ out) {
  int blk = blockIdx.x;
  if (blk < 256) {
    int s = blk * 2 + (threadIdx.x >> 8);
    int t = threadIdx.x & 255;
    int idx = (int)(~(u32)slots[s]);
    out[(size_t)s * DD + t] = feat[(size_t)idx * DD + t];
  } else {
    int b = blk - 256;
    int s = threadIdx.x;  // 0..511
    int idx = (int)(~(u32)slots[s]);
    float denom = s1p1[idx] * (float)SS;
    out[(size_t)SS * DD + (size_t)b * SS + s] = adj[(size_t)b * NN + idx] / denom;
    if (b == 255 && s == 0) out[(size_t)SS * DD + (size_t)BB * SS] = scal[1] / (float)DD;
  }
}

extern "C" void kernel_launch(void* const* d_in, const int* in_sizes, int n_in,
                              void* d_out, int out_size, void* d_ws, size_t ws_size,
                              hipStream_t stream) {
  const float* feat = (const float*)d_in[0];
  const float* adj  = (const float*)d_in[1];
  const float* w1   = (const float*)d_in[2];
  const float* w2   = (const float*)d_in[3];
  const int*   v    = (const int*)d_in[4];
  float* out = (float*)d_out;

  float* ws    = (float*)d_ws;
  float* fw2   = ws;                          // [NN] (mask rows only)
  float* s1p1  = ws + (size_t)NN;             // [NN] s1 then p1 in place (mask rows only)
  float* vlog  = ws + 2 * (size_t)NN;         // [NN]
  int*   vidx  = (int*)(ws + 3 * (size_t)NN); // [NN]
  int*   mlist = (int*)(ws + 4 * (size_t)NN); // [NN]
  u32*   umaskw = (u32*)(ws + 5 * (size_t)NN);          // [NCH*NQ] = 800000 words
  u64*   trip  = (u64*)(ws + 5 * (size_t)NN + 800000);  // [NBLK*RCAP] u64 (8B-aligned)
  u32*   tripcnt = (u32*)(ws + 5 * (size_t)NN + 800000 + 2 * (size_t)NBLK * RCAP); // [NBLK]
  float* tail  = ws + 5 * (size_t)NN + 800000 + 2 * (size_t)NBLK * RCAP + NBLK;
  float* hw1   = tail;                        // [256]
  float* means = tail + 256;                  // [256]
  float* scal  = tail + 512;                  // [16]: [0]=sum_p1 [1]=loss; ints at +2
  int*   counters = (int*)(scal + 2);         // [0]=n_mask [1]=n_valid
  u64*   slots = (u64*)(tail + 544);          // [512]

  k_adj_pass<<<NBLK, 256, 0, stream>>>(adj, umaskw, trip, tripcnt, means, scal, slots);
  k_compact<<<QB + 16, 256, 0, stream>>>(umaskw, mlist, counters, s1p1, feat, w1, v, hw1);
  k_fw2m<<<512, 256, 0, stream>>>(feat, w2, mlist, counters, fw2, means);
  k_s1<<<(NBLK + 255) / 256, 256, 0, stream>>>(trip, tripcnt, hw1, fw2, s1p1);
  k_vfin<<<128, 256, 0, stream>>>(s1p1, mlist, counters, vidx, vlog, scal);
  k_mix<<<SS * 4 + 256, 256, 0, stream>>>(vidx, vlog, counters, slots, feat, means, s1p1, scal);
  k_tail<<<512, 512, 0, stream>>>(feat, adj, s1p1, slots, scal, out);
}

// Round 11
// 176.180 us; speedup vs baseline: 1.9552x; 1.0466x over previous
//
#include <hip/hip_runtime.h>
#include <math.h>
#include <stdint.h>

#define NN 200000   // nodes
#define NQ 50000    // NN/4 column quads
#define DD 256      // feature dim
#define BB 256      // batch rows of adj
#define SS 512      // output samples
#define QB 196      // ceil(NQ/256) column blocks
#define NCH 16      // b-chunks (16 b each)
#define NBLK (QB * NCH) // 3136 adj-pass blocks
#define RCAP 64     // per-block triplet region (mean 8.2, P(>64)~1e-35)
#define MBLK 512    // means-gather blocks in k_sm
#define SBLK 784    // ceil(NBLK/4) triplet-region blocks in k_sm

// PRNG: threefry_partitionable: elem i -> tf(0, i), bits = out0 ^ out1
// (verified bit-exact PASS, absmax 0.0, rounds 2-10)
// Round-5 lesson: no RMW atomics on shared hot lines in bulk passes.
// Round-11 design: fw2 computed on-the-fly per triplet (identical dot+reduce
// bits as the old k_fw2m) -> fw2 array and one launch+stage removed; hw1
// rides inside k_adj_pass (independent of adj).

typedef unsigned int u32;
typedef unsigned long long u64;
typedef float f4 __attribute__((ext_vector_type(4)));

// ---------------- threefry2x32, key = (0,1)  (jax.random.key(1)) ----------------
__device__ __forceinline__ uint2 tf2x32(u32 x0, u32 x1) {
  const u32 ks0 = 0u, ks1 = 1u, ks2 = 0x1BD11BDBu;
  x0 += ks0; x1 += ks1;
#define TFR(r) { x0 += x1; x1 = (x1 << (r)) | (x1 >> (32 - (r))); x1 ^= x0; }
  TFR(13) TFR(15) TFR(26) TFR(6)
  x0 += ks1; x1 += ks2 + 1u;
  TFR(17) TFR(29) TFR(16) TFR(24)
  x0 += ks2; x1 += ks0 + 2u;
  TFR(13) TFR(15) TFR(26) TFR(6)
  x0 += ks0; x1 += ks1 + 3u;
  TFR(17) TFR(29) TFR(16) TFR(24)
  x0 += ks1; x1 += ks2 + 4u;
  TFR(13) TFR(15) TFR(26) TFR(6)
  x0 += ks2; x1 += ks0 + 5u;
#undef TFR
  return make_uint2(x0, x1);
}

__device__ __forceinline__ float gumbel_from_bits(u32 bits) {
  const float TINY = 1.17549435e-38f;
  float f = __uint_as_float((bits >> 9) | 0x3f800000u) - 1.0f; // [0,1)
  float x = f + TINY;
  x = fmaxf(TINY, x);
  return -logf(-logf(x));
}

// pack (gumbel g, index n) so u64-max == (argmax g, first-index tie-break)
__device__ __forceinline__ u64 pack_key(float g, int n) {
  u32 u = __float_as_uint(g);
  u32 m = (u & 0x80000000u) ? ~u : (u | 0x80000000u);
  return ((u64)m << 32) | (u32)(~(u32)n);
}

// ---------------- kernels ----------------
// FIRST kernel. blocks <NBLK: BW-bound pass over adj (per-chunk mask slices,
// fixed triplet regions, no pre-zeroed state, no global atomics); block 0 also
// zeros small scalars. blocks >=NBLK: hw1 = feat[v]@w1 (independent of adj).
__global__ __launch_bounds__(256) void k_adj_pass(const float* __restrict__ adj,
                                                  u32* __restrict__ umaskw,   // [NCH*NQ]
                                                  u64* __restrict__ trip,     // [NBLK*RCAP]
                                                  u32* __restrict__ tripcnt,  // [NBLK]
                                                  float* __restrict__ means,
                                                  float* __restrict__ scal,
                                                  u64* __restrict__ slots,
                                                  const float* __restrict__ feat,
                                                  const float* __restrict__ w1,
                                                  const int* __restrict__ v,
                                                  float* __restrict__ hw1) {
  if (blockIdx.x >= NBLK) {
    int wv = threadIdx.x >> 6;
    int lane = threadIdx.x & 63;
    int r0 = (((int)blockIdx.x - NBLK) * 4 + wv) * 4;  // rows 0..255
    f4 w4 = ((const f4*)w1)[lane];
    f4 f[4];
#pragma unroll
    for (int k = 0; k < 4; ++k)
      f[k] = ((const f4*)(feat + (size_t)v[r0 + k] * DD))[lane];
    float d[4];
#pragma unroll
    for (int k = 0; k < 4; ++k)
      d[k] = f[k].x * w4.x + f[k].y * w4.y + f[k].z * w4.z + f[k].w * w4.w;
#pragma unroll
    for (int off = 32; off; off >>= 1) {
#pragma unroll
      for (int k = 0; k < 4; ++k) d[k] += __shfl_down(d[k], off);
    }
    if (lane == 0) {
#pragma unroll
      for (int k = 0; k < 4; ++k) hw1[r0 + k] = d[k];
    }
    return;
  }
  __shared__ u32 cnt;
  if (threadIdx.x == 0) cnt = 0u;
  if (blockIdx.x == 0) {
    int t = threadIdx.x;
    for (int j = t; j < SS; j += 256) slots[j] = 0ull;
    means[t] = 0.0f;
    if (t < 16) scal[t] = 0.0f;   // includes counters aliased at scal[2..]
  }
  __syncthreads();
  int cb = blockIdx.x % QB;   // column block (1024 cols)
  int ch = blockIdx.x / QB;   // b-chunk 0..15 (16 b each)
  int b0 = ch * 16;
  int q = cb * 256 + threadIdx.x;
  u64* reg = trip + (size_t)blockIdx.x * RCAP;
  if (q < NQ) {
    const float4* adj4 = (const float4*)adj;
    float csx = 0.f, csy = 0.f, csz = 0.f, csw = 0.f;
    u32 n0 = (u32)q * 4u;
    for (int bb = 0; bb < 16; bb += 4) {
      float4 a[4];
#pragma unroll
      for (int k = 0; k < 4; ++k) a[k] = adj4[(size_t)(b0 + bb + k) * NQ + q];
#pragma unroll
      for (int k = 0; k < 4; ++k) {
        u32 b = (u32)(b0 + bb + k);
        csx += a[k].x; csy += a[k].y; csz += a[k].z; csw += a[k].w;
        if (a[k].x > 0.f) { u32 s = atomicAdd(&cnt, 1u); if (s < RCAP) reg[s] = ((u64)(((n0 + 0u) << 8) | b) << 32) | __float_as_uint(a[k].x); }
        if (a[k].y > 0.f) { u32 s = atomicAdd(&cnt, 1u); if (s < RCAP) reg[s] = ((u64)(((n0 + 1u) << 8) | b) << 32) | __float_as_uint(a[k].y); }
        if (a[k].z > 0.f) { u32 s = atomicAdd(&cnt, 1u); if (s < RCAP) reg[s] = ((u64)(((n0 + 2u) << 8) | b) << 32) | __float_as_uint(a[k].z); }
        if (a[k].w > 0.f) { u32 s = atomicAdd(&cnt, 1u); if (s < RCAP) reg[s] = ((u64)(((n0 + 3u) << 8) | b) << 32) | __float_as_uint(a[k].w); }
      }
    }
    u32 m = (csx > 0.f ? 1u : 0u) | (csy > 0.f ? 0x100u : 0u) |
            (csz > 0.f ? 0x10000u : 0u) | (csw > 0.f ? 0x1000000u : 0u);
    umaskw[(size_t)ch * NQ + q] = m;   // unconditional: slice fully covered
  }
  __syncthreads();
  if (threadIdx.x == 0) tripcnt[blockIdx.x] = cnt > RCAP ? RCAP : cnt;
}

// compact mask list (thread per quad, OR 16 slices) + zero s1 for mask rows
__global__ __launch_bounds__(256) void k_compact(const u32* __restrict__ umaskw,
                                                 int* __restrict__ mlist,
                                                 int* __restrict__ counters,
                                                 float* __restrict__ s1) {
  int q = blockIdx.x * 256 + threadIdx.x;
  u32 m = 0u;
  if (q < NQ) {
#pragma unroll
    for (int ch = 0; ch < NCH; ++ch) m |= umaskw[(size_t)ch * NQ + q];
  }
  int lane = threadIdx.x & 63;
#pragma unroll
  for (int k = 0; k < 4; ++k) {
    bool pred = ((m >> (8 * k)) & 1u) != 0u;
    u64 bm = __ballot(pred);
    int c = __popcll(bm);
    if (c) {
      int leader = __ffsll((u64)bm) - 1;
      int base = 0;
      if (lane == leader) base = atomicAdd(&counters[0], c);
      base = __shfl(base, leader);
      if (pred) {
        int n = q * 4 + k;
        mlist[base + __popcll(bm & ((1ull << lane) - 1ull))] = n;
        s1[n] = 0.0f;   // only mask rows are accumulated/read downstream
      }
    }
  }
}

// heterogeneous: blocks <MBLK means gather over mask rows; blocks >=MBLK
// wave-per-triplet-region s1 accumulation with ON-THE-FLY fw2 dot
// (identical f4-lane dot + shfl tree as the old k_fw2m -> same bits)
__global__ __launch_bounds__(256) void k_sm(const float* __restrict__ feat,
                                            const float* __restrict__ w2,
                                            const int* __restrict__ mlist,
                                            const int* __restrict__ counters,
                                            float* __restrict__ means,
                                            const u64* __restrict__ trip,
                                            const u32* __restrict__ tripcnt,
                                            const float* __restrict__ hw1,
                                            float* __restrict__ s1) {
  int blk = blockIdx.x;
  int wv = threadIdx.x >> 6;
  int lane = threadIdx.x & 63;
  if (blk < MBLK) {
    __shared__ float part[4][DD];
    int nm = counters[0];
    int wave = blk * 4 + wv;
    int stride = MBLK * 4;
    f4 acc = {0.f, 0.f, 0.f, 0.f};
    for (int j = wave; j < nm; j += stride) {
      f4 f = ((const f4*)(feat + (size_t)mlist[j] * DD))[lane];
      acc.x += f.x; acc.y += f.y; acc.z += f.z; acc.w += f.w;
    }
    ((f4*)part[wv])[lane] = acc;
    __syncthreads();
    int d = threadIdx.x;
    float vv = part[0][d] + part[1][d] + part[2][d] + part[3][d];
    atomicAdd(&means[d], vv);
  } else {
    int r = (blk - MBLK) * 4 + wv;   // triplet region = adj-pass block id
    if (r >= NBLK) return;
    u32 c = tripcnt[r];
    if (c > RCAP) c = RCAP;
    const u64* reg = trip + (size_t)r * RCAP;
    f4 w4 = ((const f4*)w2)[lane];
    for (u32 i = 0; i < c; ++i) {
      u64 t = reg[i];
      u32 key = (u32)(t >> 32);
      int n = (int)(key >> 8);
      int b = (int)(key & 255u);
      float a = __uint_as_float((u32)t);
      f4 f = ((const f4*)(feat + (size_t)n * DD))[lane];
      float d = f.x * w4.x + f.y * w4.y + f.z * w4.z + f.w * w4.w;
#pragma unroll
      for (int off = 32; off; off >>= 1) d += __shfl_down(d, off);
      if (lane == 0) {
        float val = a * fmaxf((hw1[b] + 1.0f) + d, 0.0f);
        if (val > 0.0f) atomicAdd(&s1[n], val);
      }
    }
  }
}

// fused valid-compaction + finalize over mask rows: vidx/vlog, p1 in place, sum_p1
__global__ __launch_bounds__(256) void k_vfin(float* __restrict__ s1p1,
                                              const int* __restrict__ mlist,
                                              int* __restrict__ counters,
                                              int* __restrict__ vidx,
                                              float* __restrict__ vlog,
                                              float* __restrict__ scal) {
  int nm = counters[0];
  float nnf = (float)nm;
  int lane = threadIdx.x & 63;
  float local = 0.0f;
  for (int j0 = blockIdx.x * 256; j0 < nm; j0 += gridDim.x * 256) {
    int j = j0 + threadIdx.x;
    bool on = (j < nm);
    int n = on ? mlist[j] : 0;
    float s = on ? s1p1[n] : 0.0f;
    bool pred = on && (s > 0.0f);
    u64 bm = __ballot(pred);
    int cnt = __popcll(bm);
    if (cnt) {
      int leader = __ffsll((u64)bm) - 1;
      int base = 0;
      if (lane == leader) base = atomicAdd(&counters[1], cnt);
      base = __shfl(base, leader);
      if (pred) {
        int slot = base + __popcll(bm & ((1ull << lane) - 1ull));
        float p = s / nnf;
        s1p1[n] = p;
        vidx[slot] = n;
        vlog[slot] = logf(p);
        local += p;
      }
    }
  }
#pragma unroll
  for (int off = 32; off; off >>= 1) local += __shfl_down(local, off);
  if (lane == 0 && local != 0.0f) atomicAdd(&scal[0], local);
}

// heterogeneous: blocks 0..2047 sample argmax (VALU-bound, 4 blocks/sample);
// blocks 2048..2303 loss gather (memory-bound) — loss hides under sample.
__global__ __launch_bounds__(256) void k_mix(const int* __restrict__ vidx,
                                             const float* __restrict__ vlog,
                                             const int* __restrict__ counters,
                                             u64* __restrict__ slots,
                                             const float* __restrict__ feat,
                                             const float* __restrict__ means,
                                             const float* __restrict__ s1p1,
                                             float* __restrict__ scal) {
  __shared__ u64 sk[256];
  __shared__ float ms[DD];
  int blk = blockIdx.x;
  int nv = counters[1];
  if (blk < SS * 4) {
    int s = blk >> 2;
    int quarter = blk & 3;
    u64 best = 0ull;
    u32 base = (u32)s * (u32)NN;
#pragma unroll 2
    for (int j = quarter * 256 + threadIdx.x; j < nv; j += 1024) {
      int n = vidx[j];
      uint2 r = tf2x32(0u, base + (u32)n);
      float g = gumbel_from_bits(r.x ^ r.y) + vlog[j];
      u64 key = pack_key(g, n);
      if (key > best) best = key;
    }
    sk[threadIdx.x] = best;
    __syncthreads();
#pragma unroll
    for (int off = 128; off; off >>= 1) {
      if (threadIdx.x < off) {
        u64 o = sk[threadIdx.x + off];
        if (o > sk[threadIdx.x]) sk[threadIdx.x] = o;
      }
      __syncthreads();
    }
    if (threadIdx.x == 0) atomicMax(&slots[s], sk[0]);
  } else {
    ms[threadIdx.x] = means[threadIdx.x];
    __syncthreads();
    float spu = scal[0];
    int gw = (blk - SS * 4) * 4 + (threadIdx.x >> 6);
    int tw = 256 * 4;
    int lane = threadIdx.x & 63;
    float wacc = 0.0f;
    for (int j = gw; j < nv; j += tw) {
      int r = vidx[j];
      float4 f4v = ((const float4*)(feat + (size_t)r * DD))[lane];
      float4 m4 = ((const float4*)ms)[lane];
      float dx = f4v.x - m4.x, dy = f4v.y - m4.y, dz = f4v.z - m4.z, dw = f4v.w - m4.w;
      float val = dx * dx + dy * dy + dz * dz + dw * dw;
#pragma unroll
      for (int off = 32; off; off >>= 1) val += __shfl_down(val, off);
      if (lane == 0) wacc += (s1p1[r] / spu) * val;
    }
    if (lane == 0) atomicAdd(&scal[1], wacc);
  }
}

// fused epilogue: blocks 0..255 copy x_u rows (2 samples each);
// blocks 256..511 write support row b (coalesced), gathering adj
__global__ __launch_bounds__(512) void k_tail(const float* __restrict__ feat,
                                              const float* __restrict__ adj,
                                              const float* __restrict__ s1p1,
                                              const u64* __restrict__ slots,
                                              const float* __restrict__ scal,
                                              float* __restrict__ out) {
  int blk = blockIdx.x;
  if (blk < 256) {
    int s = blk * 2 + (threadIdx.x >> 8);
    int t = threadIdx.x & 255;
    int idx = (int)(~(u32)slots[s]);
    out[(size_t)s * DD + t] = feat[(size_t)idx * DD + t];
  } else {
    int b = blk - 256;
    int s = threadIdx.x;  // 0..511
    int idx = (int)(~(u32)slots[s]);
    float denom = s1p1[idx] * (float)SS;
    out[(size_t)SS * DD + (size_t)b * SS + s] = adj[(size_t)b * NN + idx] / denom;
    if (b == 255 && s == 0) out[(size_t)SS * DD + (size_t)BB * SS] = scal[1] / (float)DD;
  }
}

extern "C" void kernel_launch(void* const* d_in, const int* in_sizes, int n_in,
                              void* d_out, int out_size, void* d_ws, size_t ws_size,
                              hipStream_t stream) {
  const float* feat = (const float*)d_in[0];
  const float* adj  = (const float*)d_in[1];
  const float* w1   = (const float*)d_in[2];
  const float* w2   = (const float*)d_in[3];
  const int*   v    = (const int*)d_in[4];
  float* out = (float*)d_out;

  float* ws    = (float*)d_ws;
  float* s1p1  = ws;                          // [NN] s1 then p1 in place (mask rows only)
  float* vlog  = ws + (size_t)NN;             // [NN]
  int*   vidx  = (int*)(ws + 2 * (size_t)NN); // [NN]
  int*   mlist = (int*)(ws + 3 * (size_t)NN); // [NN]
  u32*   umaskw = (u32*)(ws + 4 * (size_t)NN);          // [NCH*NQ] = 800000 words
  u64*   trip  = (u64*)(ws + 4 * (size_t)NN + 800000);  // [NBLK*RCAP] u64 (8B-aligned)
  u32*   tripcnt = (u32*)(ws + 4 * (size_t)NN + 800000 + 2 * (size_t)NBLK * RCAP); // [NBLK]
  float* tail  = ws + 4 * (size_t)NN + 800000 + 2 * (size_t)NBLK * RCAP + NBLK;
  float* hw1   = tail;                        // [256]
  float* means = tail + 256;                  // [256]
  float* scal  = tail + 512;                  // [16]: [0]=sum_p1 [1]=loss; ints at +2
  int*   counters = (int*)(scal + 2);         // [0]=n_mask [1]=n_valid
  u64*   slots = (u64*)(tail + 544);          // [512]

  k_adj_pass<<<NBLK + 16, 256, 0, stream>>>(adj, umaskw, trip, tripcnt, means, scal,
                                            slots, feat, w1, v, hw1);
  k_compact<<<QB, 256, 0, stream>>>(umaskw, mlist, counters, s1p1);
  k_sm<<<MBLK + SBLK, 256, 0, stream>>>(feat, w2, mlist, counters, means,
                                        trip, tripcnt, hw1, s1p1);
  k_vfin<<<128, 256, 0, stream>>>(s1p1, mlist, counters, vidx, vlog, scal);
  k_mix<<<SS * 4 + 256, 256, 0, stream>>>(vidx, vlog, counters, slots, feat, means, s1p1, scal);
  k_tail<<<512, 512, 0, stream>>>(feat, adj, s1p1, slots, scal, out);
}